// Round 10
// baseline (634.920 us; speedup 1.0000x reference)
//
#include <hip/hip_runtime.h>

#define NN 50000      // nodes
#define NE 600000     // edges
#define HC 128        // hidden channels
#define CHN 32        // chunk size
#define NG 64         // graphs
#define LN_EPS 1e-5f

typedef unsigned short ushort_t;
typedef unsigned int uint_t;

__device__ __forceinline__ ushort_t f2bf(float f) {   // RNE round to bf16
    uint_t u = __builtin_bit_cast(uint_t, f);
    u = (u + 0x7FFFu + ((u >> 16) & 1u)) >> 16;
    return (ushort_t)u;
}
__device__ __forceinline__ float bf2f(ushort_t s) {
    uint_t u = (uint_t)s << 16;
    return __builtin_bit_cast(float, u);
}
// packed pair: low16 = even channel, high16 = odd channel
__device__ __forceinline__ float bclo(uint_t u) {     // even channel
    return __builtin_bit_cast(float, u << 16);
}
__device__ __forceinline__ float bchi(uint_t u) {     // odd channel
    return __builtin_bit_cast(float, u & 0xFFFF0000u);
}
__device__ __forceinline__ uint_t pk2(float e, float o) {
    return (uint_t)f2bf(e) | ((uint_t)f2bf(o) << 16);
}

// ---------------- CSR build ----------------

__global__ void __launch_bounds__(256) k_hist(const int* __restrict__ ei, int* __restrict__ cnt) {
    int e = blockIdx.x * 256 + threadIdx.x;
    if (e >= NE) return;
    int s = ei[e], d = ei[NE + e];
    if (s != d) atomicAdd(&cnt[d], 1);
}

#define SC_BLOCKS 49   // ceil(50000/1024)

__global__ void __launch_bounds__(256) k_scanA(const int* __restrict__ cnt, int* __restrict__ blocksum) {
    int b = blockIdx.x, t = threadIdx.x;
    int idx = b * 1024 + t * 4;
    int4 v = make_int4(0, 0, 0, 0);
    if (idx + 3 < NN) v = *(const int4*)&cnt[idx];
    else {
        if (idx + 0 < NN) v.x = cnt[idx + 0];
        if (idx + 1 < NN) v.y = cnt[idx + 1];
        if (idx + 2 < NN) v.z = cnt[idx + 2];
        if (idx + 3 < NN) v.w = cnt[idx + 3];
    }
    int s = v.x + v.y + v.z + v.w;
    for (int m = 1; m < 64; m <<= 1) s += __shfl_xor(s, m, 64);
    __shared__ int ws[4];
    if ((t & 63) == 0) ws[t >> 6] = s;
    __syncthreads();
    if (t == 0) blocksum[b] = ws[0] + ws[1] + ws[2] + ws[3];
}

__global__ void __launch_bounds__(64) k_scanB(const int* __restrict__ blocksum, int* __restrict__ blockoff) {
    int t = threadIdx.x;
    int v = (t < SC_BLOCKS) ? blocksum[t] : 0;
    int inc = v;
    for (int d = 1; d < 64; d <<= 1) { int u = __shfl_up(inc, d, 64); if (t >= d) inc += u; }
    if (t < SC_BLOCKS) blockoff[t + 1] = inc;
    if (t == 0) blockoff[0] = 0;
}

__global__ void __launch_bounds__(256) k_scanC(const int* __restrict__ cnt, const int* __restrict__ blockoff,
                                               int* __restrict__ row_ptr) {
    int b = blockIdx.x, t = threadIdx.x;
    int idx = b * 1024 + t * 4;
    int4 v = make_int4(0, 0, 0, 0);
    if (idx + 3 < NN) v = *(const int4*)&cnt[idx];
    else {
        if (idx + 0 < NN) v.x = cnt[idx + 0];
        if (idx + 1 < NN) v.y = cnt[idx + 1];
        if (idx + 2 < NN) v.z = cnt[idx + 2];
        if (idx + 3 < NN) v.w = cnt[idx + 3];
    }
    int s = v.x + v.y + v.z + v.w;
    int lane = t & 63, w = t >> 6;
    int inc = s;
    for (int d = 1; d < 64; d <<= 1) { int u = __shfl_up(inc, d, 64); if (lane >= d) inc += u; }
    __shared__ int wsum[4];
    if (lane == 63) wsum[w] = inc;
    __syncthreads();
    int off = blockoff[b];
    for (int i = 0; i < w; ++i) off += wsum[i];
    int excl = off + inc - s;
    if (idx + 0 < NN) row_ptr[idx + 0] = excl;
    if (idx + 1 < NN) row_ptr[idx + 1] = excl + v.x;
    if (idx + 2 < NN) row_ptr[idx + 2] = excl + v.x + v.y;
    if (idx + 3 < NN) row_ptr[idx + 3] = excl + v.x + v.y + v.z;
    if (b == 0 && t == 0) row_ptr[NN] = blockoff[SC_BLOCKS];
}

__global__ void __launch_bounds__(256) k_fill(const int* __restrict__ ei, const int* __restrict__ row_ptr,
                                              int* __restrict__ fill, int* __restrict__ col) {
    int e = blockIdx.x * 256 + threadIdx.x;
    if (e >= NE) return;
    int s = ei[e], d = ei[NE + e];
    if (s != d) {
        int pos = atomicAdd(&fill[d], 1);
        col[row_ptr[d] + pos] = s;
    }
}

// ---------------- input MLP: h2 = bf16(LN(relu(x @ W_in + b_in))) ----------------

#define MLP_NB 8
#define MLP_GROUPS (NN / MLP_NB)   // 6250, exact

__global__ void __launch_bounds__(256) k_mlp(const float* __restrict__ x, const float* __restrict__ W,
                                             const float* __restrict__ b, const float* __restrict__ g,
                                             const float* __restrict__ be, ushort_t* __restrict__ h2) {
    __shared__ float xs[4][MLP_NB][HC];     // 16 KB
    int tid = threadIdx.x;
    int wave = tid >> 6, lane = tid & 63;
    float bx = b[2 * lane],  by = b[2 * lane + 1];
    float gx = g[2 * lane],  gy = g[2 * lane + 1];
    float bex = be[2 * lane], bey = be[2 * lane + 1];
    for (int grp = blockIdx.x * 4 + wave; grp < MLP_GROUPS; grp += gridDim.x * 4) {
        int base = grp * MLP_NB;
        #pragma unroll
        for (int nb = 0; nb < MLP_NB; ++nb) {
            float2 xv = *(const float2*)&x[(size_t)(base + nb) * HC + 2 * lane];
            *(float2*)&xs[wave][nb][2 * lane] = xv;
        }
        float ax[MLP_NB], ay[MLP_NB];
        #pragma unroll
        for (int nb = 0; nb < MLP_NB; ++nb) { ax[nb] = bx; ay[nb] = by; }
        // wave-local LDS: compiler inserts lgkmcnt waits; no block barrier needed
        for (int c = 0; c < HC; c += 4) {
            float2 wv0 = *(const float2*)&W[(c + 0) * HC + 2 * lane];
            float2 wv1 = *(const float2*)&W[(c + 1) * HC + 2 * lane];
            float2 wv2 = *(const float2*)&W[(c + 2) * HC + 2 * lane];
            float2 wv3 = *(const float2*)&W[(c + 3) * HC + 2 * lane];
            #pragma unroll
            for (int nb = 0; nb < MLP_NB; ++nb) {
                float4 xv = *(const float4*)&xs[wave][nb][c];
                ax[nb] = fmaf(xv.x, wv0.x, ax[nb]); ay[nb] = fmaf(xv.x, wv0.y, ay[nb]);
                ax[nb] = fmaf(xv.y, wv1.x, ax[nb]); ay[nb] = fmaf(xv.y, wv1.y, ay[nb]);
                ax[nb] = fmaf(xv.z, wv2.x, ax[nb]); ay[nb] = fmaf(xv.z, wv2.y, ay[nb]);
                ax[nb] = fmaf(xv.w, wv3.x, ax[nb]); ay[nb] = fmaf(xv.w, wv3.y, ay[nb]);
            }
        }
        #pragma unroll
        for (int nb = 0; nb < MLP_NB; ++nb) {
            float a0 = fmaxf(ax[nb], 0.f), a1 = fmaxf(ay[nb], 0.f);
            float sm = a0 + a1;
            for (int m = 1; m < 64; m <<= 1) sm += __shfl_xor(sm, m, 64);
            float mu = sm * (1.f / 128.f);
            float d0 = a0 - mu, d1 = a1 - mu;
            float vv = d0 * d0 + d1 * d1;
            for (int m = 1; m < 64; m <<= 1) vv += __shfl_xor(vv, m, 64);
            float inv = rsqrtf(vv * (1.f / 128.f) + LN_EPS);
            float ox = d0 * inv * gx + bex;
            float oy = d1 * inv * gy + bey;
            ushort2 o2; o2.x = f2bf(ox); o2.y = f2bf(oy);
            *(ushort2*)&h2[(size_t)(base + nb) * HC + 2 * lane] = o2;
        }
    }
}

// ---------------- fused layer: gather + mean + gating + mix + LN (bf16 state) ----------------
// One wave per node. Layout: lanes 0-31 own channels 4*l..4*l+3 (lanes 32-63 mirror).
// Gather: lanes<32 take even edges, lanes>=32 odd edges (ushort4 = half-row per
// half-wave -> 2 rows per load instr). W column (k,half) lives in 64 packed-bf16
// VGPRs; z-source hm is bf16-packed in LDS (16 b128 broadcasts/node). This cuts
// LDS-pipe ops/node ~5x vs the LDS-W version (which was LDS-issue-bound).

__global__ void __launch_bounds__(256) k_flayer(
        const ushort_t* __restrict__ h2in, ushort_t* __restrict__ h2out,
        const int* __restrict__ row_ptr, const int* __restrict__ col,
        const float* __restrict__ Wtm, const float* __restrict__ btm,
        const float* __restrict__ gall, const float* __restrict__ ball,
        float* __restrict__ tm, int layer) {
    __shared__ uint_t hm_pk[4][2][64];   // 2 KB: [wave][h|m][64 packed pairs]
    int tid = threadIdx.x;
    int wave = tid >> 6, lane = tid & 63;
    int l32 = lane & 31, half = lane >> 5;   // half: z K-split (h|m) and edge parity
    // W column k=l32, channels [half*128, half*128+128), packed bf16 pairs
    uint_t wreg[64];
    #pragma unroll 8
    for (int i = 0; i < 64; ++i) {
        int c = half * HC + 2 * i;
        wreg[i] = pk2(Wtm[c * CHN + l32], Wtm[(c + 1) * CHN + l32]);
    }
    float bk = btm[l32];
    float4 gv = *(const float4*)&gall[layer * HC + 4 * l32];
    float4 bv = *(const float4*)&ball[layer * HC + 4 * l32];
    for (int node = blockIdx.x * 4 + wave; node < NN; node += gridDim.x * 4) {
        int r0 = row_ptr[node], r1 = row_ptr[node + 1];
        int deg = r1 - r0;
        // ---- pair-row gather: this half sums edges of its parity, 4 ch/lane ----
        float a0 = 0.f, a1 = 0.f, a2 = 0.f, a3 = 0.f;
        for (int base = 0; base < deg; base += 64) {
            int nIdx = min(64, deg - base);
            int myc = (base + lane < deg) ? col[r0 + base + lane] : 0;
            int tmax = (nIdx + 1) >> 1;
            #pragma unroll 4
            for (int t = 0; t < tmax; ++t) {
                int j = 2 * t + half;
                int sj = __shfl(myc, j & 63, 64);
                bool ok = (j < nIdx);
                int sr = ok ? sj : 0;
                ushort4 v = *(const ushort4*)&h2in[(size_t)sr * HC + 4 * l32];
                float w = ok ? 1.f : 0.f;
                a0 = fmaf(w, bf2f(v.x), a0);
                a1 = fmaf(w, bf2f(v.y), a1);
                a2 = fmaf(w, bf2f(v.z), a2);
                a3 = fmaf(w, bf2f(v.w), a3);
            }
        }
        // combine parities: both halves end with full sums
        a0 += __shfl_xor(a0, 32, 64);
        a1 += __shfl_xor(a1, 32, 64);
        a2 += __shfl_xor(a2, 32, 64);
        a3 += __shfl_xor(a3, 32, 64);
        // ---- self row, mean ----
        ushort4 hv4 = *(const ushort4*)&h2in[(size_t)node * HC + 4 * l32];
        float h0 = bf2f(hv4.x), h1 = bf2f(hv4.y), h2v = bf2f(hv4.z), h3 = bf2f(hv4.w);
        float invdeg = 1.f / (float)(deg + 1);
        float m0 = (a0 + h0) * invdeg, m1 = (a1 + h1) * invdeg;
        float m2 = (a2 + h2v) * invdeg, m3 = (a3 + h3) * invdeg;
        if (half == 0) {
            uint2 hp; hp.x = pk2(h0, h1); hp.y = pk2(h2v, h3);
            uint2 mp; mp.x = pk2(m0, m1); mp.y = pk2(m2, m3);
            *(uint2*)&hm_pk[wave][0][2 * l32] = hp;
            *(uint2*)&hm_pk[wave][1][2 * l32] = mp;
        }
        // wave-local LDS: compiler inserts the lgkmcnt wait; no block barrier needed
        // ---- z_k: half 0 = h . W[0:128,k], half 1 = m . W[128:256,k] ----
        const uint_t* sp = &hm_pk[wave][half][0];
        float z = 0.f;
        #pragma unroll
        for (int i = 0; i < 16; ++i) {
            uint4 s4 = *(const uint4*)&sp[4 * i];   // broadcast (uniform per half)
            z = fmaf(bclo(s4.x), bclo(wreg[4 * i + 0]), z);
            z = fmaf(bchi(s4.x), bchi(wreg[4 * i + 0]), z);
            z = fmaf(bclo(s4.y), bclo(wreg[4 * i + 1]), z);
            z = fmaf(bchi(s4.y), bchi(wreg[4 * i + 1]), z);
            z = fmaf(bclo(s4.z), bclo(wreg[4 * i + 2]), z);
            z = fmaf(bchi(s4.z), bchi(wreg[4 * i + 2]), z);
            z = fmaf(bclo(s4.w), bclo(wreg[4 * i + 3]), z);
            z = fmaf(bchi(s4.w), bchi(wreg[4 * i + 3]), z);
        }
        z += __shfl_xor(z, 32, 64);      // combine halves -> full z on all lanes
        z += bk;
        // ---- softmax over 32 gates (width-32: halves identical) ----
        float mx = z;
        for (int m = 1; m < 32; m <<= 1) mx = fmaxf(mx, __shfl_xor(mx, m, 32));
        float e = expf(z - mx);
        float se = e;
        for (int m = 1; m < 32; m <<= 1) se += __shfl_xor(se, m, 32);
        float p = e / se;
        // inclusive cumsum over gate index
        float cum = p;
        for (int d = 1; d < 32; d <<= 1) {
            float t2 = __shfl_up(cum, d, 32);
            if (l32 >= d) cum += t2;
        }
        float tmo = tm[(size_t)node * CHN + l32];
        float raw = tmo + (1.f - tmo) * cum;
        if (half == 0) tm[(size_t)node * CHN + l32] = raw;
        // sig for this lane's 4 channels = raw at gate l32 (since r = H/CH = 4)
        float sig = __shfl(raw, l32, 64);
        float om = 1.f - sig;
        float v0 = h0 * sig + m0 * om;
        float v1 = h1 * sig + m1 * om;
        float v2 = h2v * sig + m2 * om;
        float v3 = h3 * sig + m3 * om;
        // ---- LN over 128 ch: width-32 reduce (each half holds a full copy) ----
        float sm = v0 + v1 + v2 + v3;
        for (int m = 1; m < 32; m <<= 1) sm += __shfl_xor(sm, m, 32);
        float mu = sm * (1.f / 128.f);
        float d0 = v0 - mu, d1 = v1 - mu, d2 = v2 - mu, d3 = v3 - mu;
        float vv = d0 * d0 + d1 * d1 + d2 * d2 + d3 * d3;
        for (int m = 1; m < 32; m <<= 1) vv += __shfl_xor(vv, m, 32);
        float inv = rsqrtf(vv * (1.f / 128.f) + LN_EPS);
        if (half == 0) {
            ushort4 o4;
            o4.x = f2bf(d0 * inv * gv.x + bv.x);
            o4.y = f2bf(d1 * inv * gv.y + bv.y);
            o4.z = f2bf(d2 * inv * gv.z + bv.z);
            o4.w = f2bf(d3 * inv * gv.w + bv.w);
            *(ushort4*)&h2out[(size_t)node * HC + 4 * l32] = o4;
        }
    }
}

// ---------------- global mean pool (batch is sorted), bf16 input ----------------

__global__ void __launch_bounds__(1024) k_pool(const ushort_t* __restrict__ h2, const int* __restrict__ batch,
                                               float* __restrict__ out) {
    __shared__ float red[8][HC];
    int g = blockIdx.x;
    int tid = threadIdx.x;
    int c = tid & (HC - 1);
    int w = tid >> 7;          // 0..7 node-slice
    int a = 0, bnd = NN;
    while (a < bnd) { int mid = (a + bnd) >> 1; if (batch[mid] < g) a = mid + 1; else bnd = mid; }
    int start = a;
    bnd = NN;
    while (a < bnd) { int mid = (a + bnd) >> 1; if (batch[mid] <= g) a = mid + 1; else bnd = mid; }
    int end = a;
    float acc = 0.f;
    for (int n = start + w; n < end; n += 8) acc += bf2f(h2[(size_t)n * HC + c]);
    red[w][c] = acc;
    __syncthreads();
    if (w == 0) {
        float s = red[0][c] + red[1][c] + red[2][c] + red[3][c]
                + red[4][c] + red[5][c] + red[6][c] + red[7][c];
        int count = end - start;
        out[g * HC + c] = s / (float)max(count, 1);
    }
}

// ---------------- launch ----------------

extern "C" void kernel_launch(void* const* d_in, const int* in_sizes, int n_in,
                              void* d_out, int out_size, void* d_ws, size_t ws_size,
                              hipStream_t stream) {
    const float* x     = (const float*)d_in[0];
    const int*   ei    = (const int*)d_in[1];
    const int*   batch = (const int*)d_in[2];
    const float* W_in  = (const float*)d_in[3];
    const float* b_in  = (const float*)d_in[4];
    const float* g_in  = (const float*)d_in[5];
    const float* be_in = (const float*)d_in[6];
    const float* W_tm  = (const float*)d_in[7];
    const float* b_tm  = (const float*)d_in[8];
    const float* tm_g  = (const float*)d_in[9];
    const float* tm_b  = (const float*)d_in[10];
    float* out = (float*)d_out;

    char* ws = (char*)d_ws;
    int*      cnt = (int*)(ws + 0);              // NN ints
    int*      fil = (int*)(ws + 200000);         // NN ints
    int*      rp  = (int*)(ws + 400000);         // NN+1 ints
    int*      col = (int*)(ws + 600004);         // NE ints   (ends at 3,000,004)
    ushort_t* h2A = (ushort_t*)(ws + 3000064);   // NN*HC bf16 (12.8 MB)
    ushort_t* h2B = (ushort_t*)(ws + 15800064);  // NN*HC bf16 (12.8 MB)
    float*    tm  = (float*)(ws + 28600064);     // NN*CHN fp32 (6.4 MB) -> 35,000,064
    int*      bsum = (int*)(ws + 35000064);      // SC_BLOCKS ints
    int*      boff = (int*)(ws + 35000320);      // SC_BLOCKS+1 ints

    hipMemsetAsync(cnt, 0, 400000, stream);       // cnt + fil (contiguous)
    hipMemsetAsync(tm, 0, 6400000, stream);       // last_tm_signal = 0

    k_hist<<<(NE + 255) / 256, 256, 0, stream>>>(ei, cnt);
    k_scanA<<<SC_BLOCKS, 256, 0, stream>>>(cnt, bsum);
    k_scanB<<<1, 64, 0, stream>>>(bsum, boff);
    k_scanC<<<SC_BLOCKS, 256, 0, stream>>>(cnt, boff, rp);
    k_fill<<<(NE + 255) / 256, 256, 0, stream>>>(ei, rp, fil, col);

    k_mlp<<<1563, 256, 0, stream>>>(x, W_in, b_in, g_in, be_in, h2A);

    k_flayer<<<2048, 256, 0, stream>>>(h2A, h2B, rp, col, W_tm, b_tm, tm_g, tm_b, tm, 0);
    k_flayer<<<2048, 256, 0, stream>>>(h2B, h2A, rp, col, W_tm, b_tm, tm_g, tm_b, tm, 1);
    k_flayer<<<2048, 256, 0, stream>>>(h2A, h2B, rp, col, W_tm, b_tm, tm_g, tm_b, tm, 2);

    k_pool<<<NG, 1024, 0, stream>>>(h2B, batch, out);
}

// Round 11
// 502.320 us; speedup vs baseline: 1.2640x; 1.2640x over previous
//
#include <hip/hip_runtime.h>

#define NN 50000      // nodes
#define NE 600000     // edges
#define HC 128        // hidden channels
#define CHN 32        // chunk size
#define NG 64         // graphs
#define LN_EPS 1e-5f

typedef unsigned short ushort_t;
typedef unsigned int uint_t;

__device__ __forceinline__ ushort_t f2bf(float f) {   // RNE round to bf16
    uint_t u = __builtin_bit_cast(uint_t, f);
    u = (u + 0x7FFFu + ((u >> 16) & 1u)) >> 16;
    return (ushort_t)u;
}
__device__ __forceinline__ float bf2f(ushort_t s) {
    uint_t u = (uint_t)s << 16;
    return __builtin_bit_cast(float, u);
}
// packed pair: low16 = even channel, high16 = odd channel
__device__ __forceinline__ float bclo(uint_t u) {
    return __builtin_bit_cast(float, u << 16);
}
__device__ __forceinline__ float bchi(uint_t u) {
    return __builtin_bit_cast(float, u & 0xFFFF0000u);
}
__device__ __forceinline__ uint_t pk2(float e, float o) {
    return (uint_t)f2bf(e) | ((uint_t)f2bf(o) << 16);
}

// ---------------- CSR build ----------------

__global__ void __launch_bounds__(256) k_hist(const int* __restrict__ ei, int* __restrict__ cnt) {
    int e = blockIdx.x * 256 + threadIdx.x;
    if (e >= NE) return;
    int s = ei[e], d = ei[NE + e];
    if (s != d) atomicAdd(&cnt[d], 1);
}

#define SC_BLOCKS 49   // ceil(50000/1024)

__global__ void __launch_bounds__(256) k_scanA(const int* __restrict__ cnt, int* __restrict__ blocksum) {
    int b = blockIdx.x, t = threadIdx.x;
    int idx = b * 1024 + t * 4;
    int4 v = make_int4(0, 0, 0, 0);
    if (idx + 3 < NN) v = *(const int4*)&cnt[idx];
    else {
        if (idx + 0 < NN) v.x = cnt[idx + 0];
        if (idx + 1 < NN) v.y = cnt[idx + 1];
        if (idx + 2 < NN) v.z = cnt[idx + 2];
        if (idx + 3 < NN) v.w = cnt[idx + 3];
    }
    int s = v.x + v.y + v.z + v.w;
    for (int m = 1; m < 64; m <<= 1) s += __shfl_xor(s, m, 64);
    __shared__ int ws[4];
    if ((t & 63) == 0) ws[t >> 6] = s;
    __syncthreads();
    if (t == 0) blocksum[b] = ws[0] + ws[1] + ws[2] + ws[3];
}

__global__ void __launch_bounds__(64) k_scanB(const int* __restrict__ blocksum, int* __restrict__ blockoff) {
    int t = threadIdx.x;
    int v = (t < SC_BLOCKS) ? blocksum[t] : 0;
    int inc = v;
    for (int d = 1; d < 64; d <<= 1) { int u = __shfl_up(inc, d, 64); if (t >= d) inc += u; }
    if (t < SC_BLOCKS) blockoff[t + 1] = inc;
    if (t == 0) blockoff[0] = 0;
}

__global__ void __launch_bounds__(256) k_scanC(const int* __restrict__ cnt, const int* __restrict__ blockoff,
                                               int* __restrict__ row_ptr) {
    int b = blockIdx.x, t = threadIdx.x;
    int idx = b * 1024 + t * 4;
    int4 v = make_int4(0, 0, 0, 0);
    if (idx + 3 < NN) v = *(const int4*)&cnt[idx];
    else {
        if (idx + 0 < NN) v.x = cnt[idx + 0];
        if (idx + 1 < NN) v.y = cnt[idx + 1];
        if (idx + 2 < NN) v.z = cnt[idx + 2];
        if (idx + 3 < NN) v.w = cnt[idx + 3];
    }
    int s = v.x + v.y + v.z + v.w;
    int lane = t & 63, w = t >> 6;
    int inc = s;
    for (int d = 1; d < 64; d <<= 1) { int u = __shfl_up(inc, d, 64); if (lane >= d) inc += u; }
    __shared__ int wsum[4];
    if (lane == 63) wsum[w] = inc;
    __syncthreads();
    int off = blockoff[b];
    for (int i = 0; i < w; ++i) off += wsum[i];
    int excl = off + inc - s;
    if (idx + 0 < NN) row_ptr[idx + 0] = excl;
    if (idx + 1 < NN) row_ptr[idx + 1] = excl + v.x;
    if (idx + 2 < NN) row_ptr[idx + 2] = excl + v.x + v.y;
    if (idx + 3 < NN) row_ptr[idx + 3] = excl + v.x + v.y + v.z;
    if (b == 0 && t == 0) row_ptr[NN] = blockoff[SC_BLOCKS];
}

__global__ void __launch_bounds__(256) k_fill(const int* __restrict__ ei, const int* __restrict__ row_ptr,
                                              int* __restrict__ fill, int* __restrict__ col) {
    int e = blockIdx.x * 256 + threadIdx.x;
    if (e >= NE) return;
    int s = ei[e], d = ei[NE + e];
    if (s != d) {
        int pos = atomicAdd(&fill[d], 1);
        col[row_ptr[d] + pos] = s;
    }
}

// ---------------- input MLP: h2 = bf16(LN(relu(x @ W_in + b_in))) ----------------

#define MLP_NB 8
#define MLP_GROUPS (NN / MLP_NB)   // 6250, exact

__global__ void __launch_bounds__(256) k_mlp(const float* __restrict__ x, const float* __restrict__ W,
                                             const float* __restrict__ b, const float* __restrict__ g,
                                             const float* __restrict__ be, ushort_t* __restrict__ h2) {
    __shared__ float xs[4][MLP_NB][HC];     // 16 KB
    int tid = threadIdx.x;
    int wave = tid >> 6, lane = tid & 63;
    float bx = b[2 * lane],  by = b[2 * lane + 1];
    float gx = g[2 * lane],  gy = g[2 * lane + 1];
    float bex = be[2 * lane], bey = be[2 * lane + 1];
    for (int grp = blockIdx.x * 4 + wave; grp < MLP_GROUPS; grp += gridDim.x * 4) {
        int base = grp * MLP_NB;
        #pragma unroll
        for (int nb = 0; nb < MLP_NB; ++nb) {
            float2 xv = *(const float2*)&x[(size_t)(base + nb) * HC + 2 * lane];
            *(float2*)&xs[wave][nb][2 * lane] = xv;
        }
        float ax[MLP_NB], ay[MLP_NB];
        #pragma unroll
        for (int nb = 0; nb < MLP_NB; ++nb) { ax[nb] = bx; ay[nb] = by; }
        // wave-local LDS: compiler inserts lgkmcnt waits; no block barrier needed
        for (int c = 0; c < HC; c += 4) {
            float2 wv0 = *(const float2*)&W[(c + 0) * HC + 2 * lane];
            float2 wv1 = *(const float2*)&W[(c + 1) * HC + 2 * lane];
            float2 wv2 = *(const float2*)&W[(c + 2) * HC + 2 * lane];
            float2 wv3 = *(const float2*)&W[(c + 3) * HC + 2 * lane];
            #pragma unroll
            for (int nb = 0; nb < MLP_NB; ++nb) {
                float4 xv = *(const float4*)&xs[wave][nb][c];
                ax[nb] = fmaf(xv.x, wv0.x, ax[nb]); ay[nb] = fmaf(xv.x, wv0.y, ay[nb]);
                ax[nb] = fmaf(xv.y, wv1.x, ax[nb]); ay[nb] = fmaf(xv.y, wv1.y, ay[nb]);
                ax[nb] = fmaf(xv.z, wv2.x, ax[nb]); ay[nb] = fmaf(xv.z, wv2.y, ay[nb]);
                ax[nb] = fmaf(xv.w, wv3.x, ax[nb]); ay[nb] = fmaf(xv.w, wv3.y, ay[nb]);
            }
        }
        #pragma unroll
        for (int nb = 0; nb < MLP_NB; ++nb) {
            float a0 = fmaxf(ax[nb], 0.f), a1 = fmaxf(ay[nb], 0.f);
            float sm = a0 + a1;
            for (int m = 1; m < 64; m <<= 1) sm += __shfl_xor(sm, m, 64);
            float mu = sm * (1.f / 128.f);
            float d0 = a0 - mu, d1 = a1 - mu;
            float vv = d0 * d0 + d1 * d1;
            for (int m = 1; m < 64; m <<= 1) vv += __shfl_xor(vv, m, 64);
            float inv = rsqrtf(vv * (1.f / 128.f) + LN_EPS);
            float ox = d0 * inv * gx + bex;
            float oy = d1 * inv * gy + bey;
            ushort2 o2; o2.x = f2bf(ox); o2.y = f2bf(oy);
            *(ushort2*)&h2[(size_t)(base + nb) * HC + 2 * lane] = o2;
        }
    }
}

// ---------------- fused layer: gather + mean + gating + mix + LN (bf16 state) ----------------
// Round-9 structure (2 ch/lane, proven gather) with two changes:
//  (a) W column in 64 u32 VGPRs — init and use loops FULLY unrolled so every
//      index is compile-time constant (no scratch; round-10 spill lesson).
//  (b) hm staged bf16-packed in LDS (2 KB): 16 b128 broadcasts + 2 b32 writes
//      per node instead of 64 scalar W reads + 32 b128 reads.
// DS-pipe model: ~446 cy/node vs round 9's ~990 -> ~36 us + VMEM gather floor.

__global__ void __launch_bounds__(256) k_flayer(
        const ushort_t* __restrict__ h2in, ushort_t* __restrict__ h2out,
        const int* __restrict__ row_ptr, const int* __restrict__ col,
        const float* __restrict__ Wtm, const float* __restrict__ btm,
        const float* __restrict__ gall, const float* __restrict__ ball,
        float* __restrict__ tm, int layer) {
    __shared__ uint_t hm_pk[4][2][64];   // 2 KB: [wave][h|m][pair]
    int tid = threadIdx.x;
    int wave = tid >> 6, lane = tid & 63;
    int k = lane & 31, half = lane >> 5;
    // W column: gate k, channels [half*128, half*128+128) as 64 packed pairs.
    // FULL unroll -> static indices -> stays in VGPRs. Loads are lane-coalesced.
    uint_t wreg[64];
    #pragma unroll
    for (int i = 0; i < 64; ++i) {
        int c = half * HC + 2 * i;
        wreg[i] = pk2(Wtm[c * CHN + k], Wtm[(c + 1) * CHN + k]);
    }
    float bk  = btm[k];
    float gx  = gall[layer * HC + 2 * lane], gy  = gall[layer * HC + 2 * lane + 1];
    float bex = ball[layer * HC + 2 * lane], bey = ball[layer * HC + 2 * lane + 1];
    for (int node = blockIdx.x * 4 + wave; node < NN; node += gridDim.x * 4) {
        int r0 = row_ptr[node], r1 = row_ptr[node + 1];
        int deg = r1 - r0;
        // ---- gather-sum over in-neighbors (round-9 proven pattern) ----
        float ax = 0.f, ay = 0.f;
        for (int base = 0; base < deg; base += 64) {
            int nIdx = min(64, deg - base);
            int myc = (base + lane < deg) ? col[r0 + base + lane] : 0;
            int j = 0;
            for (; j + 4 <= nIdx; j += 4) {
                int s0 = __shfl(myc, j,     64);
                int s1 = __shfl(myc, j + 1, 64);
                int s2 = __shfl(myc, j + 2, 64);
                int s3 = __shfl(myc, j + 3, 64);
                ushort2 v0 = *(const ushort2*)&h2in[(size_t)s0 * HC + 2 * lane];
                ushort2 v1 = *(const ushort2*)&h2in[(size_t)s1 * HC + 2 * lane];
                ushort2 v2 = *(const ushort2*)&h2in[(size_t)s2 * HC + 2 * lane];
                ushort2 v3 = *(const ushort2*)&h2in[(size_t)s3 * HC + 2 * lane];
                ax += bf2f(v0.x); ay += bf2f(v0.y);
                ax += bf2f(v1.x); ay += bf2f(v1.y);
                ax += bf2f(v2.x); ay += bf2f(v2.y);
                ax += bf2f(v3.x); ay += bf2f(v3.y);
            }
            for (; j < nIdx; ++j) {
                int s = __shfl(myc, j, 64);
                ushort2 hv2 = *(const ushort2*)&h2in[(size_t)s * HC + 2 * lane];
                ax += bf2f(hv2.x); ay += bf2f(hv2.y);
            }
        }
        // ---- self row, mean ----
        ushort2 hv2 = *(const ushort2*)&h2in[(size_t)node * HC + 2 * lane];
        float h0 = bf2f(hv2.x), h1 = bf2f(hv2.y);
        float tmo = tm[(size_t)node * CHN + k];
        float invdeg = 1.f / (float)(deg + 1);
        float m0 = (ax + h0) * invdeg, m1 = (ay + h1) * invdeg;
        // stage bf16-packed [h|m] (pair index = lane)
        hm_pk[wave][0][lane] = pk2(h0, h1);
        hm_pk[wave][1][lane] = pk2(m0, m1);
        // wave-local LDS: compiler inserts the lgkmcnt wait; no block barrier needed
        // ---- z_k: half 0 = h . W[0:128,k], half 1 = m . W[128:256,k] ----
        const uint_t* sp = &hm_pk[wave][half][0];
        float z = 0.f;
        #pragma unroll
        for (int i = 0; i < 16; ++i) {
            uint4 s4 = *(const uint4*)&sp[4 * i];   // broadcast (uniform per half)
            z = fmaf(bclo(s4.x), bclo(wreg[4 * i + 0]), z);
            z = fmaf(bchi(s4.x), bchi(wreg[4 * i + 0]), z);
            z = fmaf(bclo(s4.y), bclo(wreg[4 * i + 1]), z);
            z = fmaf(bchi(s4.y), bchi(wreg[4 * i + 1]), z);
            z = fmaf(bclo(s4.z), bclo(wreg[4 * i + 2]), z);
            z = fmaf(bchi(s4.z), bchi(wreg[4 * i + 2]), z);
            z = fmaf(bclo(s4.w), bclo(wreg[4 * i + 3]), z);
            z = fmaf(bchi(s4.w), bchi(wreg[4 * i + 3]), z);
        }
        z += __shfl_xor(z, 32, 64);      // combine halves -> full z_k on all lanes
        z += bk;
        // ---- softmax over 32 gates (width-32: halves identical) ----
        float mx = z;
        for (int m = 1; m < 32; m <<= 1) mx = fmaxf(mx, __shfl_xor(mx, m, 32));
        float e = expf(z - mx);
        float se = e;
        for (int m = 1; m < 32; m <<= 1) se += __shfl_xor(se, m, 32);
        float p = e / se;
        // inclusive cumsum over gate index
        float cum = p;
        for (int d = 1; d < 32; d <<= 1) {
            float t2 = __shfl_up(cum, d, 32);
            if (k >= d) cum += t2;
        }
        float raw = tmo + (1.f - tmo) * cum;
        if (half == 0) tm[(size_t)node * CHN + k] = raw;
        // sig for channels (2*lane, 2*lane+1): gate = lane>>1
        float sig = __shfl(raw, lane >> 1, 64);
        float v0 = h0 * sig + m0 * (1.f - sig);
        float v1 = h1 * sig + m1 * (1.f - sig);
        // ---- LN over 128 ch (width-64 reduce, 2 ch/lane) ----
        float sm = v0 + v1;
        for (int m = 1; m < 64; m <<= 1) sm += __shfl_xor(sm, m, 64);
        float mu = sm * (1.f / 128.f);
        float d0 = v0 - mu, d1 = v1 - mu;
        float vv = d0 * d0 + d1 * d1;
        for (int m = 1; m < 64; m <<= 1) vv += __shfl_xor(vv, m, 64);
        float inv = rsqrtf(vv * (1.f / 128.f) + LN_EPS);
        ushort2 o2;
        o2.x = f2bf(d0 * inv * gx + bex);
        o2.y = f2bf(d1 * inv * gy + bey);
        *(ushort2*)&h2out[(size_t)node * HC + 2 * lane] = o2;
    }
}

// ---------------- global mean pool (batch is sorted), bf16 input ----------------

__global__ void __launch_bounds__(1024) k_pool(const ushort_t* __restrict__ h2, const int* __restrict__ batch,
                                               float* __restrict__ out) {
    __shared__ float red[8][HC];
    int g = blockIdx.x;
    int tid = threadIdx.x;
    int c = tid & (HC - 1);
    int w = tid >> 7;          // 0..7 node-slice
    int a = 0, bnd = NN;
    while (a < bnd) { int mid = (a + bnd) >> 1; if (batch[mid] < g) a = mid + 1; else bnd = mid; }
    int start = a;
    bnd = NN;
    while (a < bnd) { int mid = (a + bnd) >> 1; if (batch[mid] <= g) a = mid + 1; else bnd = mid; }
    int end = a;
    float acc = 0.f;
    for (int n = start + w; n < end; n += 8) acc += bf2f(h2[(size_t)n * HC + c]);
    red[w][c] = acc;
    __syncthreads();
    if (w == 0) {
        float s = red[0][c] + red[1][c] + red[2][c] + red[3][c]
                + red[4][c] + red[5][c] + red[6][c] + red[7][c];
        int count = end - start;
        out[g * HC + c] = s / (float)max(count, 1);
    }
}

// ---------------- launch ----------------

extern "C" void kernel_launch(void* const* d_in, const int* in_sizes, int n_in,
                              void* d_out, int out_size, void* d_ws, size_t ws_size,
                              hipStream_t stream) {
    const float* x     = (const float*)d_in[0];
    const int*   ei    = (const int*)d_in[1];
    const int*   batch = (const int*)d_in[2];
    const float* W_in  = (const float*)d_in[3];
    const float* b_in  = (const float*)d_in[4];
    const float* g_in  = (const float*)d_in[5];
    const float* be_in = (const float*)d_in[6];
    const float* W_tm  = (const float*)d_in[7];
    const float* b_tm  = (const float*)d_in[8];
    const float* tm_g  = (const float*)d_in[9];
    const float* tm_b  = (const float*)d_in[10];
    float* out = (float*)d_out;

    char* ws = (char*)d_ws;
    int*      cnt = (int*)(ws + 0);              // NN ints
    int*      fil = (int*)(ws + 200000);         // NN ints
    int*      rp  = (int*)(ws + 400000);         // NN+1 ints
    int*      col = (int*)(ws + 600004);         // NE ints   (ends at 3,000,004)
    ushort_t* h2A = (ushort_t*)(ws + 3000064);   // NN*HC bf16 (12.8 MB)
    ushort_t* h2B = (ushort_t*)(ws + 15800064);  // NN*HC bf16 (12.8 MB)
    float*    tm  = (float*)(ws + 28600064);     // NN*CHN fp32 (6.4 MB) -> 35,000,064
    int*      bsum = (int*)(ws + 35000064);      // SC_BLOCKS ints
    int*      boff = (int*)(ws + 35000320);      // SC_BLOCKS+1 ints

    hipMemsetAsync(cnt, 0, 400000, stream);       // cnt + fil (contiguous)
    hipMemsetAsync(tm, 0, 6400000, stream);       // last_tm_signal = 0

    k_hist<<<(NE + 255) / 256, 256, 0, stream>>>(ei, cnt);
    k_scanA<<<SC_BLOCKS, 256, 0, stream>>>(cnt, bsum);
    k_scanB<<<1, 64, 0, stream>>>(bsum, boff);
    k_scanC<<<SC_BLOCKS, 256, 0, stream>>>(cnt, boff, rp);
    k_fill<<<(NE + 255) / 256, 256, 0, stream>>>(ei, rp, fil, col);

    k_mlp<<<1563, 256, 0, stream>>>(x, W_in, b_in, g_in, be_in, h2A);

    k_flayer<<<2048, 256, 0, stream>>>(h2A, h2B, rp, col, W_tm, b_tm, tm_g, tm_b, tm, 0);
    k_flayer<<<2048, 256, 0, stream>>>(h2B, h2A, rp, col, W_tm, b_tm, tm_g, tm_b, tm, 1);
    k_flayer<<<2048, 256, 0, stream>>>(h2A, h2B, rp, col, W_tm, b_tm, tm_g, tm_b, tm, 2);

    k_pool<<<NG, 1024, 0, stream>>>(h2B, batch, out);
}

// Round 12
// 488.138 us; speedup vs baseline: 1.3007x; 1.0291x over previous
//
#include <hip/hip_runtime.h>

#define NN 50000      // nodes
#define NE 600000     // edges
#define HC 128        // hidden channels
#define CHN 32        // chunk size
#define NG 64         // graphs
#define LN_EPS 1e-5f

typedef unsigned short ushort_t;
typedef unsigned int uint_t;

__device__ __forceinline__ ushort_t f2bf(float f) {   // RNE round to bf16
    uint_t u = __builtin_bit_cast(uint_t, f);
    u = (u + 0x7FFFu + ((u >> 16) & 1u)) >> 16;
    return (ushort_t)u;
}
__device__ __forceinline__ float bf2f(ushort_t s) {
    uint_t u = (uint_t)s << 16;
    return __builtin_bit_cast(float, u);
}
// packed pair: low16 = even channel, high16 = odd channel
__device__ __forceinline__ float bclo(uint_t u) {
    return __builtin_bit_cast(float, u << 16);
}
__device__ __forceinline__ float bchi(uint_t u) {
    return __builtin_bit_cast(float, u & 0xFFFF0000u);
}
__device__ __forceinline__ uint_t pk2(float e, float o) {
    return (uint_t)f2bf(e) | ((uint_t)f2bf(o) << 16);
}

// ---------------- CSR build ----------------

__global__ void __launch_bounds__(256) k_hist(const int* __restrict__ ei, int* __restrict__ cnt) {
    int e = blockIdx.x * 256 + threadIdx.x;
    if (e >= NE) return;
    int s = ei[e], d = ei[NE + e];
    if (s != d) atomicAdd(&cnt[d], 1);
}

#define SC_BLOCKS 49   // ceil(50000/1024)

__global__ void __launch_bounds__(256) k_scanA(const int* __restrict__ cnt, int* __restrict__ blocksum) {
    int b = blockIdx.x, t = threadIdx.x;
    int idx = b * 1024 + t * 4;
    int4 v = make_int4(0, 0, 0, 0);
    if (idx + 3 < NN) v = *(const int4*)&cnt[idx];
    else {
        if (idx + 0 < NN) v.x = cnt[idx + 0];
        if (idx + 1 < NN) v.y = cnt[idx + 1];
        if (idx + 2 < NN) v.z = cnt[idx + 2];
        if (idx + 3 < NN) v.w = cnt[idx + 3];
    }
    int s = v.x + v.y + v.z + v.w;
    for (int m = 1; m < 64; m <<= 1) s += __shfl_xor(s, m, 64);
    __shared__ int ws[4];
    if ((t & 63) == 0) ws[t >> 6] = s;
    __syncthreads();
    if (t == 0) blocksum[b] = ws[0] + ws[1] + ws[2] + ws[3];
}

__global__ void __launch_bounds__(64) k_scanB(const int* __restrict__ blocksum, int* __restrict__ blockoff) {
    int t = threadIdx.x;
    int v = (t < SC_BLOCKS) ? blocksum[t] : 0;
    int inc = v;
    for (int d = 1; d < 64; d <<= 1) { int u = __shfl_up(inc, d, 64); if (t >= d) inc += u; }
    if (t < SC_BLOCKS) blockoff[t + 1] = inc;
    if (t == 0) blockoff[0] = 0;
}

__global__ void __launch_bounds__(256) k_scanC(const int* __restrict__ cnt, const int* __restrict__ blockoff,
                                               int* __restrict__ row_ptr) {
    int b = blockIdx.x, t = threadIdx.x;
    int idx = b * 1024 + t * 4;
    int4 v = make_int4(0, 0, 0, 0);
    if (idx + 3 < NN) v = *(const int4*)&cnt[idx];
    else {
        if (idx + 0 < NN) v.x = cnt[idx + 0];
        if (idx + 1 < NN) v.y = cnt[idx + 1];
        if (idx + 2 < NN) v.z = cnt[idx + 2];
        if (idx + 3 < NN) v.w = cnt[idx + 3];
    }
    int s = v.x + v.y + v.z + v.w;
    int lane = t & 63, w = t >> 6;
    int inc = s;
    for (int d = 1; d < 64; d <<= 1) { int u = __shfl_up(inc, d, 64); if (lane >= d) inc += u; }
    __shared__ int wsum[4];
    if (lane == 63) wsum[w] = inc;
    __syncthreads();
    int off = blockoff[b];
    for (int i = 0; i < w; ++i) off += wsum[i];
    int excl = off + inc - s;
    if (idx + 0 < NN) row_ptr[idx + 0] = excl;
    if (idx + 1 < NN) row_ptr[idx + 1] = excl + v.x;
    if (idx + 2 < NN) row_ptr[idx + 2] = excl + v.x + v.y;
    if (idx + 3 < NN) row_ptr[idx + 3] = excl + v.x + v.y + v.z;
    if (b == 0 && t == 0) row_ptr[NN] = blockoff[SC_BLOCKS];
}

__global__ void __launch_bounds__(256) k_fill(const int* __restrict__ ei, const int* __restrict__ row_ptr,
                                              int* __restrict__ fill, int* __restrict__ col) {
    int e = blockIdx.x * 256 + threadIdx.x;
    if (e >= NE) return;
    int s = ei[e], d = ei[NE + e];
    if (s != d) {
        int pos = atomicAdd(&fill[d], 1);
        col[row_ptr[d] + pos] = s;
    }
}

// ---------------- input MLP: h2 = bf16(LN(relu(x @ W_in + b_in))) ----------------

#define MLP_NB 8
#define MLP_GROUPS (NN / MLP_NB)   // 6250, exact

__global__ void __launch_bounds__(256) k_mlp(const float* __restrict__ x, const float* __restrict__ W,
                                             const float* __restrict__ b, const float* __restrict__ g,
                                             const float* __restrict__ be, ushort_t* __restrict__ h2) {
    __shared__ float xs[4][MLP_NB][HC];     // 16 KB
    int tid = threadIdx.x;
    int wave = tid >> 6, lane = tid & 63;
    float bx = b[2 * lane],  by = b[2 * lane + 1];
    float gx = g[2 * lane],  gy = g[2 * lane + 1];
    float bex = be[2 * lane], bey = be[2 * lane + 1];
    for (int grp = blockIdx.x * 4 + wave; grp < MLP_GROUPS; grp += gridDim.x * 4) {
        int base = grp * MLP_NB;
        #pragma unroll
        for (int nb = 0; nb < MLP_NB; ++nb) {
            float2 xv = *(const float2*)&x[(size_t)(base + nb) * HC + 2 * lane];
            *(float2*)&xs[wave][nb][2 * lane] = xv;
        }
        float ax[MLP_NB], ay[MLP_NB];
        #pragma unroll
        for (int nb = 0; nb < MLP_NB; ++nb) { ax[nb] = bx; ay[nb] = by; }
        // wave-local LDS: compiler inserts lgkmcnt waits; no block barrier needed
        for (int c = 0; c < HC; c += 4) {
            float2 wv0 = *(const float2*)&W[(c + 0) * HC + 2 * lane];
            float2 wv1 = *(const float2*)&W[(c + 1) * HC + 2 * lane];
            float2 wv2 = *(const float2*)&W[(c + 2) * HC + 2 * lane];
            float2 wv3 = *(const float2*)&W[(c + 3) * HC + 2 * lane];
            #pragma unroll
            for (int nb = 0; nb < MLP_NB; ++nb) {
                float4 xv = *(const float4*)&xs[wave][nb][c];
                ax[nb] = fmaf(xv.x, wv0.x, ax[nb]); ay[nb] = fmaf(xv.x, wv0.y, ay[nb]);
                ax[nb] = fmaf(xv.y, wv1.x, ax[nb]); ay[nb] = fmaf(xv.y, wv1.y, ay[nb]);
                ax[nb] = fmaf(xv.z, wv2.x, ax[nb]); ay[nb] = fmaf(xv.z, wv2.y, ay[nb]);
                ax[nb] = fmaf(xv.w, wv3.x, ax[nb]); ay[nb] = fmaf(xv.w, wv3.y, ay[nb]);
            }
        }
        #pragma unroll
        for (int nb = 0; nb < MLP_NB; ++nb) {
            float a0 = fmaxf(ax[nb], 0.f), a1 = fmaxf(ay[nb], 0.f);
            float sm = a0 + a1;
            for (int m = 1; m < 64; m <<= 1) sm += __shfl_xor(sm, m, 64);
            float mu = sm * (1.f / 128.f);
            float d0 = a0 - mu, d1 = a1 - mu;
            float vv = d0 * d0 + d1 * d1;
            for (int m = 1; m < 64; m <<= 1) vv += __shfl_xor(vv, m, 64);
            float inv = rsqrtf(vv * (1.f / 128.f) + LN_EPS);
            float ox = d0 * inv * gx + bex;
            float oy = d1 * inv * gy + bey;
            ushort2 o2; o2.x = f2bf(ox); o2.y = f2bf(oy);
            *(ushort2*)&h2[(size_t)(base + nb) * HC + 2 * lane] = o2;
        }
    }
}

// ---------------- fused layer: gather + mean + gating + mix + LN (bf16 state) ----------------
// Round-9 structure (W in LDS [cp][k] -> bank k, conflict-free; lean VGPR so the
// latency-bound gather keeps ~8 waves/SIMD) with two DS-count cuts:
//  (a) TWO nodes per wave iteration: each scalar W read feeds both z dots
//      (W reads 64 -> 32 per node).
//  (b) hm staged bf16-PACKED (4 KB): 8 b128 broadcast reads per node (was 32).
// All hot loops fully unrolled, no runtime-indexed register arrays (spill rule).

__global__ void __launch_bounds__(256) k_flayer(
        const ushort_t* __restrict__ h2in, ushort_t* __restrict__ h2out,
        const int* __restrict__ row_ptr, const int* __restrict__ col,
        const float* __restrict__ Wtm, const float* __restrict__ btm,
        const float* __restrict__ gall, const float* __restrict__ ball,
        float* __restrict__ tm, int layer) {
    __shared__ uint_t Wpk[2 * HC / 2 * CHN / CHN][CHN];  // placeholder dims below
    // real dims: Wpk[128][32] packed bf16 pairs of the 256x32 weight
    __shared__ uint_t hm_pk[4][2][2][64];   // 4 KB: [wave][node][h|m][pair]
    int tid = threadIdx.x;
    // stage packed W: entry m -> cp = m>>5 (0..127), gate = m&31
    for (int m = tid; m < 128 * CHN; m += 256) {
        int cp = m >> 5, kk = m & 31;
        Wpk[cp][kk] = pk2(Wtm[(2 * cp) * CHN + kk], Wtm[(2 * cp + 1) * CHN + kk]);
    }
    __syncthreads();
    int wave = tid >> 6, lane = tid & 63;
    int k = lane & 31, half = lane >> 5;
    float bk  = btm[k];
    float gx  = gall[layer * HC + 2 * lane], gy  = gall[layer * HC + 2 * lane + 1];
    float bex = ball[layer * HC + 2 * lane], bey = ball[layer * HC + 2 * lane + 1];
    for (int pr = blockIdx.x * 4 + wave; pr < NN / 2; pr += gridDim.x * 4) {
        int n0 = 2 * pr;
        float hxA, hyA, mxA, myA, tmoA;
        float hxB, hyB, mxB, myB, tmoB;
        #pragma unroll
        for (int nb = 0; nb < 2; ++nb) {
            int node = n0 + nb;
            int r0 = row_ptr[node], r1 = row_ptr[node + 1];
            int deg = r1 - r0;
            float tmo = tm[(size_t)node * CHN + k];   // prefetch (hides under gather)
            float ax = 0.f, ay = 0.f;
            for (int base = 0; base < deg; base += 64) {
                int nIdx = min(64, deg - base);
                int myc = (base + lane < deg) ? col[r0 + base + lane] : 0;
                int j = 0;
                for (; j + 4 <= nIdx; j += 4) {
                    int s0 = __shfl(myc, j,     64);
                    int s1 = __shfl(myc, j + 1, 64);
                    int s2 = __shfl(myc, j + 2, 64);
                    int s3 = __shfl(myc, j + 3, 64);
                    ushort2 v0 = *(const ushort2*)&h2in[(size_t)s0 * HC + 2 * lane];
                    ushort2 v1 = *(const ushort2*)&h2in[(size_t)s1 * HC + 2 * lane];
                    ushort2 v2 = *(const ushort2*)&h2in[(size_t)s2 * HC + 2 * lane];
                    ushort2 v3 = *(const ushort2*)&h2in[(size_t)s3 * HC + 2 * lane];
                    ax += bf2f(v0.x); ay += bf2f(v0.y);
                    ax += bf2f(v1.x); ay += bf2f(v1.y);
                    ax += bf2f(v2.x); ay += bf2f(v2.y);
                    ax += bf2f(v3.x); ay += bf2f(v3.y);
                }
                for (; j < nIdx; ++j) {
                    int s = __shfl(myc, j, 64);
                    ushort2 hv2 = *(const ushort2*)&h2in[(size_t)s * HC + 2 * lane];
                    ax += bf2f(hv2.x); ay += bf2f(hv2.y);
                }
            }
            ushort2 hv2 = *(const ushort2*)&h2in[(size_t)node * HC + 2 * lane];
            float h0 = bf2f(hv2.x), h1 = bf2f(hv2.y);
            float invdeg = 1.f / (float)(deg + 1);
            float m0 = (ax + h0) * invdeg, m1 = (ay + h1) * invdeg;
            hm_pk[wave][nb][0][lane] = pk2(h0, h1);
            hm_pk[wave][nb][1][lane] = pk2(m0, m1);
            if (nb == 0) { hxA = h0; hyA = h1; mxA = m0; myA = m1; tmoA = tmo; }
            else         { hxB = h0; hyB = h1; mxB = m0; myB = m1; tmoB = tmo; }
        }
        // wave-local LDS: compiler inserts the lgkmcnt wait; no block barrier needed
        // ---- z for both nodes: half 0 = h . W[0:128,k], half 1 = m . W[128:256,k] ----
        const uint_t* spA = &hm_pk[wave][0][half][0];
        const uint_t* spB = &hm_pk[wave][1][half][0];
        float zA = 0.f, zB = 0.f;
        #pragma unroll
        for (int i = 0; i < 16; ++i) {
            uint4 sa = *(const uint4*)&spA[4 * i];   // broadcast
            uint4 sb = *(const uint4*)&spB[4 * i];
            uint_t w0 = Wpk[half * 64 + 4 * i + 0][k];   // bank k, conflict-free
            uint_t w1 = Wpk[half * 64 + 4 * i + 1][k];
            uint_t w2 = Wpk[half * 64 + 4 * i + 2][k];
            uint_t w3 = Wpk[half * 64 + 4 * i + 3][k];
            zA = fmaf(bclo(sa.x), bclo(w0), zA); zA = fmaf(bchi(sa.x), bchi(w0), zA);
            zA = fmaf(bclo(sa.y), bclo(w1), zA); zA = fmaf(bchi(sa.y), bchi(w1), zA);
            zA = fmaf(bclo(sa.z), bclo(w2), zA); zA = fmaf(bchi(sa.z), bchi(w2), zA);
            zA = fmaf(bclo(sa.w), bclo(w3), zA); zA = fmaf(bchi(sa.w), bchi(w3), zA);
            zB = fmaf(bclo(sb.x), bclo(w0), zB); zB = fmaf(bchi(sb.x), bchi(w0), zB);
            zB = fmaf(bclo(sb.y), bclo(w1), zB); zB = fmaf(bchi(sb.y), bchi(w1), zB);
            zB = fmaf(bclo(sb.z), bclo(w2), zB); zB = fmaf(bchi(sb.z), bchi(w2), zB);
            zB = fmaf(bclo(sb.w), bclo(w3), zB); zB = fmaf(bchi(sb.w), bchi(w3), zB);
        }
        #pragma unroll
        for (int nb = 0; nb < 2; ++nb) {
            float z   = nb ? zB  : zA;
            float h0  = nb ? hxB : hxA,  h1 = nb ? hyB : hyA;
            float m0  = nb ? mxB : mxA,  m1 = nb ? myB : myA;
            float tmo = nb ? tmoB : tmoA;
            z += __shfl_xor(z, 32, 64);      // combine halves -> full z_k on all lanes
            z += bk;
            // softmax over 32 gates (width-32: halves identical)
            float mx = z;
            for (int m = 1; m < 32; m <<= 1) mx = fmaxf(mx, __shfl_xor(mx, m, 32));
            float e = expf(z - mx);
            float se = e;
            for (int m = 1; m < 32; m <<= 1) se += __shfl_xor(se, m, 32);
            float p = e / se;
            // inclusive cumsum over gate index
            float cum = p;
            for (int d = 1; d < 32; d <<= 1) {
                float t2 = __shfl_up(cum, d, 32);
                if (k >= d) cum += t2;
            }
            float raw = tmo + (1.f - tmo) * cum;
            if (half == 0) tm[(size_t)(n0 + nb) * CHN + k] = raw;
            // sig for channels (2*lane, 2*lane+1): gate = lane>>1
            float sig = __shfl(raw, lane >> 1, 64);
            float v0 = h0 * sig + m0 * (1.f - sig);
            float v1 = h1 * sig + m1 * (1.f - sig);
            // LN over 128 ch (width-64 reduce, 2 ch/lane)
            float sm = v0 + v1;
            for (int m = 1; m < 64; m <<= 1) sm += __shfl_xor(sm, m, 64);
            float mu = sm * (1.f / 128.f);
            float d0 = v0 - mu, d1 = v1 - mu;
            float vv = d0 * d0 + d1 * d1;
            for (int m = 1; m < 64; m <<= 1) vv += __shfl_xor(vv, m, 64);
            float inv = rsqrtf(vv * (1.f / 128.f) + LN_EPS);
            ushort2 o2;
            o2.x = f2bf(d0 * inv * gx + bex);
            o2.y = f2bf(d1 * inv * gy + bey);
            *(ushort2*)&h2out[(size_t)(n0 + nb) * HC + 2 * lane] = o2;
        }
    }
}

// ---------------- global mean pool (batch is sorted), bf16 input ----------------

__global__ void __launch_bounds__(1024) k_pool(const ushort_t* __restrict__ h2, const int* __restrict__ batch,
                                               float* __restrict__ out) {
    __shared__ float red[8][HC];
    int g = blockIdx.x;
    int tid = threadIdx.x;
    int c = tid & (HC - 1);
    int w = tid >> 7;          // 0..7 node-slice
    int a = 0, bnd = NN;
    while (a < bnd) { int mid = (a + bnd) >> 1; if (batch[mid] < g) a = mid + 1; else bnd = mid; }
    int start = a;
    bnd = NN;
    while (a < bnd) { int mid = (a + bnd) >> 1; if (batch[mid] <= g) a = mid + 1; else bnd = mid; }
    int end = a;
    float acc = 0.f;
    for (int n = start + w; n < end; n += 8) acc += bf2f(h2[(size_t)n * HC + c]);
    red[w][c] = acc;
    __syncthreads();
    if (w == 0) {
        float s = red[0][c] + red[1][c] + red[2][c] + red[3][c]
                + red[4][c] + red[5][c] + red[6][c] + red[7][c];
        int count = end - start;
        out[g * HC + c] = s / (float)max(count, 1);
    }
}

// ---------------- launch ----------------

extern "C" void kernel_launch(void* const* d_in, const int* in_sizes, int n_in,
                              void* d_out, int out_size, void* d_ws, size_t ws_size,
                              hipStream_t stream) {
    const float* x     = (const float*)d_in[0];
    const int*   ei    = (const int*)d_in[1];
    const int*   batch = (const int*)d_in[2];
    const float* W_in  = (const float*)d_in[3];
    const float* b_in  = (const float*)d_in[4];
    const float* g_in  = (const float*)d_in[5];
    const float* be_in = (const float*)d_in[6];
    const float* W_tm  = (const float*)d_in[7];
    const float* b_tm  = (const float*)d_in[8];
    const float* tm_g  = (const float*)d_in[9];
    const float* tm_b  = (const float*)d_in[10];
    float* out = (float*)d_out;

    char* ws = (char*)d_ws;
    int*      cnt = (int*)(ws + 0);              // NN ints
    int*      fil = (int*)(ws + 200000);         // NN ints
    int*      rp  = (int*)(ws + 400000);         // NN+1 ints
    int*      col = (int*)(ws + 600004);         // NE ints   (ends at 3,000,004)
    ushort_t* h2A = (ushort_t*)(ws + 3000064);   // NN*HC bf16 (12.8 MB)
    ushort_t* h2B = (ushort_t*)(ws + 15800064);  // NN*HC bf16 (12.8 MB)
    float*    tm  = (float*)(ws + 28600064);     // NN*CHN fp32 (6.4 MB) -> 35,000,064
    int*      bsum = (int*)(ws + 35000064);      // SC_BLOCKS ints
    int*      boff = (int*)(ws + 35000320);      // SC_BLOCKS+1 ints

    hipMemsetAsync(cnt, 0, 400000, stream);       // cnt + fil (contiguous)
    hipMemsetAsync(tm, 0, 6400000, stream);       // last_tm_signal = 0

    k_hist<<<(NE + 255) / 256, 256, 0, stream>>>(ei, cnt);
    k_scanA<<<SC_BLOCKS, 256, 0, stream>>>(cnt, bsum);
    k_scanB<<<1, 64, 0, stream>>>(bsum, boff);
    k_scanC<<<SC_BLOCKS, 256, 0, stream>>>(cnt, boff, rp);
    k_fill<<<(NE + 255) / 256, 256, 0, stream>>>(ei, rp, fil, col);

    k_mlp<<<1563, 256, 0, stream>>>(x, W_in, b_in, g_in, be_in, h2A);

    k_flayer<<<2048, 256, 0, stream>>>(h2A, h2B, rp, col, W_tm, b_tm, tm_g, tm_b, tm, 0);
    k_flayer<<<2048, 256, 0, stream>>>(h2B, h2A, rp, col, W_tm, b_tm, tm_g, tm_b, tm, 1);
    k_flayer<<<2048, 256, 0, stream>>>(h2A, h2B, rp, col, W_tm, b_tm, tm_g, tm_b, tm, 2);

    k_pool<<<NG, 1024, 0, stream>>>(h2B, batch, out);
}

// Round 13
// 318.607 us; speedup vs baseline: 1.9928x; 1.5321x over previous
//
#include <hip/hip_runtime.h>

#define NN 50000      // nodes
#define NE 600000     // edges
#define HC 128        // hidden channels
#define CHN 32        // chunk size
#define NG 64         // graphs
#define LN_EPS 1e-5f

typedef unsigned short ushort_t;
typedef unsigned int uint_t;

__device__ __forceinline__ ushort_t f2bf(float f) {   // RNE round to bf16
    uint_t u = __builtin_bit_cast(uint_t, f);
    u = (u + 0x7FFFu + ((u >> 16) & 1u)) >> 16;
    return (ushort_t)u;
}
__device__ __forceinline__ float bf2f(ushort_t s) {
    uint_t u = (uint_t)s << 16;
    return __builtin_bit_cast(float, u);
}
// packed pair: low16 = even channel, high16 = odd channel
__device__ __forceinline__ float bclo(uint_t u) {
    return __builtin_bit_cast(float, u << 16);
}
__device__ __forceinline__ float bchi(uint_t u) {
    return __builtin_bit_cast(float, u & 0xFFFF0000u);
}
__device__ __forceinline__ uint_t pk2(float e, float o) {
    return (uint_t)f2bf(e) | ((uint_t)f2bf(o) << 16);
}

// ---------------- CSR build ----------------

__global__ void __launch_bounds__(256) k_hist(const int* __restrict__ ei, int* __restrict__ cnt) {
    int e = blockIdx.x * 256 + threadIdx.x;
    if (e >= NE) return;
    int s = ei[e], d = ei[NE + e];
    if (s != d) atomicAdd(&cnt[d], 1);
}

#define SC_BLOCKS 49   // ceil(50000/1024)

__global__ void __launch_bounds__(256) k_scanA(const int* __restrict__ cnt, int* __restrict__ blocksum) {
    int b = blockIdx.x, t = threadIdx.x;
    int idx = b * 1024 + t * 4;
    int4 v = make_int4(0, 0, 0, 0);
    if (idx + 3 < NN) v = *(const int4*)&cnt[idx];
    else {
        if (idx + 0 < NN) v.x = cnt[idx + 0];
        if (idx + 1 < NN) v.y = cnt[idx + 1];
        if (idx + 2 < NN) v.z = cnt[idx + 2];
        if (idx + 3 < NN) v.w = cnt[idx + 3];
    }
    int s = v.x + v.y + v.z + v.w;
    for (int m = 1; m < 64; m <<= 1) s += __shfl_xor(s, m, 64);
    __shared__ int ws[4];
    if ((t & 63) == 0) ws[t >> 6] = s;
    __syncthreads();
    if (t == 0) blocksum[b] = ws[0] + ws[1] + ws[2] + ws[3];
}

__global__ void __launch_bounds__(64) k_scanB(const int* __restrict__ blocksum, int* __restrict__ blockoff) {
    int t = threadIdx.x;
    int v = (t < SC_BLOCKS) ? blocksum[t] : 0;
    int inc = v;
    for (int d = 1; d < 64; d <<= 1) { int u = __shfl_up(inc, d, 64); if (t >= d) inc += u; }
    if (t < SC_BLOCKS) blockoff[t + 1] = inc;
    if (t == 0) blockoff[0] = 0;
}

__global__ void __launch_bounds__(256) k_scanC(const int* __restrict__ cnt, const int* __restrict__ blockoff,
                                               int* __restrict__ row_ptr) {
    int b = blockIdx.x, t = threadIdx.x;
    int idx = b * 1024 + t * 4;
    int4 v = make_int4(0, 0, 0, 0);
    if (idx + 3 < NN) v = *(const int4*)&cnt[idx];
    else {
        if (idx + 0 < NN) v.x = cnt[idx + 0];
        if (idx + 1 < NN) v.y = cnt[idx + 1];
        if (idx + 2 < NN) v.z = cnt[idx + 2];
        if (idx + 3 < NN) v.w = cnt[idx + 3];
    }
    int s = v.x + v.y + v.z + v.w;
    int lane = t & 63, w = t >> 6;
    int inc = s;
    for (int d = 1; d < 64; d <<= 1) { int u = __shfl_up(inc, d, 64); if (lane >= d) inc += u; }
    __shared__ int wsum[4];
    if (lane == 63) wsum[w] = inc;
    __syncthreads();
    int off = blockoff[b];
    for (int i = 0; i < w; ++i) off += wsum[i];
    int excl = off + inc - s;
    if (idx + 0 < NN) row_ptr[idx + 0] = excl;
    if (idx + 1 < NN) row_ptr[idx + 1] = excl + v.x;
    if (idx + 2 < NN) row_ptr[idx + 2] = excl + v.x + v.y;
    if (idx + 3 < NN) row_ptr[idx + 3] = excl + v.x + v.y + v.z;
    if (b == 0 && t == 0) row_ptr[NN] = blockoff[SC_BLOCKS];
}

__global__ void __launch_bounds__(256) k_fill(const int* __restrict__ ei, const int* __restrict__ row_ptr,
                                              int* __restrict__ fill, int* __restrict__ col) {
    int e = blockIdx.x * 256 + threadIdx.x;
    if (e >= NE) return;
    int s = ei[e], d = ei[NE + e];
    if (s != d) {
        int pos = atomicAdd(&fill[d], 1);
        col[row_ptr[d] + pos] = s;
    }
}

// ---------------- pack W_tm once: Wg[cp*32+k] = bf16pair(W[2cp][k], W[2cp+1][k]) ----------------

__global__ void __launch_bounds__(256) k_prepW(const float* __restrict__ Wtm, uint_t* __restrict__ Wg) {
    int i = blockIdx.x * 256 + threadIdx.x;
    if (i >= (HC / 2) * 2 * CHN) return;          // 128*32 = 4096 entries
    int cp = i >> 5, kk = i & 31;
    Wg[i] = pk2(Wtm[(2 * cp) * CHN + kk], Wtm[(2 * cp + 1) * CHN + kk]);
}

// ---------------- input MLP: h2 = bf16(LN(relu(x @ W_in + b_in))) ----------------

#define MLP_NB 8
#define MLP_GROUPS (NN / MLP_NB)   // 6250, exact

__global__ void __launch_bounds__(256) k_mlp(const float* __restrict__ x, const float* __restrict__ W,
                                             const float* __restrict__ b, const float* __restrict__ g,
                                             const float* __restrict__ be, ushort_t* __restrict__ h2) {
    __shared__ float xs[4][MLP_NB][HC];     // 16 KB
    int tid = threadIdx.x;
    int wave = tid >> 6, lane = tid & 63;
    float bx = b[2 * lane],  by = b[2 * lane + 1];
    float gx = g[2 * lane],  gy = g[2 * lane + 1];
    float bex = be[2 * lane], bey = be[2 * lane + 1];
    for (int grp = blockIdx.x * 4 + wave; grp < MLP_GROUPS; grp += gridDim.x * 4) {
        int base = grp * MLP_NB;
        #pragma unroll
        for (int nb = 0; nb < MLP_NB; ++nb) {
            float2 xv = *(const float2*)&x[(size_t)(base + nb) * HC + 2 * lane];
            *(float2*)&xs[wave][nb][2 * lane] = xv;
        }
        float ax[MLP_NB], ay[MLP_NB];
        #pragma unroll
        for (int nb = 0; nb < MLP_NB; ++nb) { ax[nb] = bx; ay[nb] = by; }
        // wave-local LDS: compiler inserts lgkmcnt waits; no block barrier needed
        for (int c = 0; c < HC; c += 4) {
            float2 wv0 = *(const float2*)&W[(c + 0) * HC + 2 * lane];
            float2 wv1 = *(const float2*)&W[(c + 1) * HC + 2 * lane];
            float2 wv2 = *(const float2*)&W[(c + 2) * HC + 2 * lane];
            float2 wv3 = *(const float2*)&W[(c + 3) * HC + 2 * lane];
            #pragma unroll
            for (int nb = 0; nb < MLP_NB; ++nb) {
                float4 xv = *(const float4*)&xs[wave][nb][c];
                ax[nb] = fmaf(xv.x, wv0.x, ax[nb]); ay[nb] = fmaf(xv.x, wv0.y, ay[nb]);
                ax[nb] = fmaf(xv.y, wv1.x, ax[nb]); ay[nb] = fmaf(xv.y, wv1.y, ay[nb]);
                ax[nb] = fmaf(xv.z, wv2.x, ax[nb]); ay[nb] = fmaf(xv.z, wv2.y, ay[nb]);
                ax[nb] = fmaf(xv.w, wv3.x, ax[nb]); ay[nb] = fmaf(xv.w, wv3.y, ay[nb]);
            }
        }
        #pragma unroll
        for (int nb = 0; nb < MLP_NB; ++nb) {
            float a0 = fmaxf(ax[nb], 0.f), a1 = fmaxf(ay[nb], 0.f);
            float sm = a0 + a1;
            for (int m = 1; m < 64; m <<= 1) sm += __shfl_xor(sm, m, 64);
            float mu = sm * (1.f / 128.f);
            float d0 = a0 - mu, d1 = a1 - mu;
            float vv = d0 * d0 + d1 * d1;
            for (int m = 1; m < 64; m <<= 1) vv += __shfl_xor(vv, m, 64);
            float inv = rsqrtf(vv * (1.f / 128.f) + LN_EPS);
            float ox = d0 * inv * gx + bex;
            float oy = d1 * inv * gy + bey;
            ushort2 o2; o2.x = f2bf(ox); o2.y = f2bf(oy);
            *(ushort2*)&h2[(size_t)(base + nb) * HC + 2 * lane] = o2;
        }
    }
}

// ---------------- fused layer: gather + mean + gating + mix + LN (bf16 state) ----------------
// Occupancy-first design (R9->R12 lesson: flayer time tracks wave count, not
// DS-op count). R8 k_agg scheduling shape: ONE node per wave, 12500 blocks,
// no grid-stride, no W staging (W read from pre-packed global -> L1-resident
// 16 KB, coalesced per half-wave). LDS = 2 KB hm only. Target VGPR <= 72.

__global__ void __launch_bounds__(256) k_flayer(
        const ushort_t* __restrict__ h2in, ushort_t* __restrict__ h2out,
        const int* __restrict__ row_ptr, const int* __restrict__ col,
        const uint_t* __restrict__ Wg, const float* __restrict__ btm,
        const float* __restrict__ gall, const float* __restrict__ ball,
        float* __restrict__ tm, int layer) {
    __shared__ uint_t hm_pk[4][2][64];   // 2 KB: [wave][h|m][pair]
    int tid = threadIdx.x;
    int wave = tid >> 6, lane = tid & 63;
    int k = lane & 31, half = lane >> 5;
    int node = blockIdx.x * 4 + wave;
    int r0 = row_ptr[node], r1 = row_ptr[node + 1];
    int deg = r1 - r0;
    float tmo = tm[(size_t)node * CHN + k];   // prefetch, hides under gather
    float bk  = btm[k];
    float gx  = gall[layer * HC + 2 * lane], gy  = gall[layer * HC + 2 * lane + 1];
    float bex = ball[layer * HC + 2 * lane], bey = ball[layer * HC + 2 * lane + 1];
    // ---- gather-sum over in-neighbors (R8/R9 proven pattern) ----
    float ax = 0.f, ay = 0.f;
    for (int base = 0; base < deg; base += 64) {
        int nIdx = min(64, deg - base);
        int myc = (base + lane < deg) ? col[r0 + base + lane] : 0;
        int j = 0;
        for (; j + 4 <= nIdx; j += 4) {
            int s0 = __shfl(myc, j,     64);
            int s1 = __shfl(myc, j + 1, 64);
            int s2 = __shfl(myc, j + 2, 64);
            int s3 = __shfl(myc, j + 3, 64);
            ushort2 v0 = *(const ushort2*)&h2in[(size_t)s0 * HC + 2 * lane];
            ushort2 v1 = *(const ushort2*)&h2in[(size_t)s1 * HC + 2 * lane];
            ushort2 v2 = *(const ushort2*)&h2in[(size_t)s2 * HC + 2 * lane];
            ushort2 v3 = *(const ushort2*)&h2in[(size_t)s3 * HC + 2 * lane];
            ax += bf2f(v0.x); ay += bf2f(v0.y);
            ax += bf2f(v1.x); ay += bf2f(v1.y);
            ax += bf2f(v2.x); ay += bf2f(v2.y);
            ax += bf2f(v3.x); ay += bf2f(v3.y);
        }
        for (; j < nIdx; ++j) {
            int s = __shfl(myc, j, 64);
            ushort2 hv2 = *(const ushort2*)&h2in[(size_t)s * HC + 2 * lane];
            ax += bf2f(hv2.x); ay += bf2f(hv2.y);
        }
    }
    // ---- self row, mean ----
    ushort2 hv2 = *(const ushort2*)&h2in[(size_t)node * HC + 2 * lane];
    float h0 = bf2f(hv2.x), h1 = bf2f(hv2.y);
    float invdeg = 1.f / (float)(deg + 1);
    float m0 = (ax + h0) * invdeg, m1 = (ay + h1) * invdeg;
    hm_pk[wave][0][lane] = pk2(h0, h1);
    hm_pk[wave][1][lane] = pk2(m0, m1);
    // wave-local LDS: compiler inserts the lgkmcnt wait; no block barrier needed
    // ---- z_k: half 0 = h . W[0:128,k], half 1 = m . W[128:256,k] ----
    // W from global: lanes 0-31 read consecutive u32 (coalesced 128B/half), L1-hot.
    const uint_t* sp = &hm_pk[wave][half][0];
    const uint_t* wp = Wg + (size_t)(half * 64) * CHN + k;
    float z = 0.f;
    #pragma unroll
    for (int i = 0; i < 16; ++i) {
        uint4 s4 = *(const uint4*)&sp[4 * i];       // LDS broadcast
        uint_t w0 = wp[(4 * i + 0) * CHN];
        uint_t w1 = wp[(4 * i + 1) * CHN];
        uint_t w2 = wp[(4 * i + 2) * CHN];
        uint_t w3 = wp[(4 * i + 3) * CHN];
        z = fmaf(bclo(s4.x), bclo(w0), z); z = fmaf(bchi(s4.x), bchi(w0), z);
        z = fmaf(bclo(s4.y), bclo(w1), z); z = fmaf(bchi(s4.y), bchi(w1), z);
        z = fmaf(bclo(s4.z), bclo(w2), z); z = fmaf(bchi(s4.z), bchi(w2), z);
        z = fmaf(bclo(s4.w), bclo(w3), z); z = fmaf(bchi(s4.w), bchi(w3), z);
    }
    z += __shfl_xor(z, 32, 64);      // combine halves -> full z_k on all lanes
    z += bk;
    // ---- softmax over 32 gates (width-32: halves identical) ----
    float mx = z;
    for (int m = 1; m < 32; m <<= 1) mx = fmaxf(mx, __shfl_xor(mx, m, 32));
    float e = expf(z - mx);
    float se = e;
    for (int m = 1; m < 32; m <<= 1) se += __shfl_xor(se, m, 32);
    float p = e / se;
    // inclusive cumsum over gate index
    float cum = p;
    for (int d = 1; d < 32; d <<= 1) {
        float t2 = __shfl_up(cum, d, 32);
        if (k >= d) cum += t2;
    }
    float raw = tmo + (1.f - tmo) * cum;
    if (half == 0) tm[(size_t)node * CHN + k] = raw;
    // sig for channels (2*lane, 2*lane+1): gate = lane>>1
    float sig = __shfl(raw, lane >> 1, 64);
    float v0 = h0 * sig + m0 * (1.f - sig);
    float v1 = h1 * sig + m1 * (1.f - sig);
    // ---- LN over 128 ch (width-64 reduce, 2 ch/lane) ----
    float sm = v0 + v1;
    for (int m = 1; m < 64; m <<= 1) sm += __shfl_xor(sm, m, 64);
    float mu = sm * (1.f / 128.f);
    float d0 = v0 - mu, d1 = v1 - mu;
    float vv = d0 * d0 + d1 * d1;
    for (int m = 1; m < 64; m <<= 1) vv += __shfl_xor(vv, m, 64);
    float inv = rsqrtf(vv * (1.f / 128.f) + LN_EPS);
    ushort2 o2;
    o2.x = f2bf(d0 * inv * gx + bex);
    o2.y = f2bf(d1 * inv * gy + bey);
    *(ushort2*)&h2out[(size_t)node * HC + 2 * lane] = o2;
}

// ---------------- global mean pool (batch is sorted), bf16 input ----------------

__global__ void __launch_bounds__(1024) k_pool(const ushort_t* __restrict__ h2, const int* __restrict__ batch,
                                               float* __restrict__ out) {
    __shared__ float red[8][HC];
    int g = blockIdx.x;
    int tid = threadIdx.x;
    int c = tid & (HC - 1);
    int w = tid >> 7;          // 0..7 node-slice
    int a = 0, bnd = NN;
    while (a < bnd) { int mid = (a + bnd) >> 1; if (batch[mid] < g) a = mid + 1; else bnd = mid; }
    int start = a;
    bnd = NN;
    while (a < bnd) { int mid = (a + bnd) >> 1; if (batch[mid] <= g) a = mid + 1; else bnd = mid; }
    int end = a;
    float acc = 0.f;
    for (int n = start + w; n < end; n += 8) acc += bf2f(h2[(size_t)n * HC + c]);
    red[w][c] = acc;
    __syncthreads();
    if (w == 0) {
        float s = red[0][c] + red[1][c] + red[2][c] + red[3][c]
                + red[4][c] + red[5][c] + red[6][c] + red[7][c];
        int count = end - start;
        out[g * HC + c] = s / (float)max(count, 1);
    }
}

// ---------------- launch ----------------

extern "C" void kernel_launch(void* const* d_in, const int* in_sizes, int n_in,
                              void* d_out, int out_size, void* d_ws, size_t ws_size,
                              hipStream_t stream) {
    const float* x     = (const float*)d_in[0];
    const int*   ei    = (const int*)d_in[1];
    const int*   batch = (const int*)d_in[2];
    const float* W_in  = (const float*)d_in[3];
    const float* b_in  = (const float*)d_in[4];
    const float* g_in  = (const float*)d_in[5];
    const float* be_in = (const float*)d_in[6];
    const float* W_tm  = (const float*)d_in[7];
    const float* b_tm  = (const float*)d_in[8];
    const float* tm_g  = (const float*)d_in[9];
    const float* tm_b  = (const float*)d_in[10];
    float* out = (float*)d_out;

    char* ws = (char*)d_ws;
    int*      cnt = (int*)(ws + 0);              // NN ints
    int*      fil = (int*)(ws + 200000);         // NN ints
    int*      rp  = (int*)(ws + 400000);         // NN+1 ints
    int*      col = (int*)(ws + 600004);         // NE ints   (ends at 3,000,004)
    ushort_t* h2A = (ushort_t*)(ws + 3000064);   // NN*HC bf16 (12.8 MB)
    ushort_t* h2B = (ushort_t*)(ws + 15800064);  // NN*HC bf16 (12.8 MB)
    float*    tm  = (float*)(ws + 28600064);     // NN*CHN fp32 (6.4 MB) -> 35,000,064
    int*      bsum = (int*)(ws + 35000064);      // SC_BLOCKS ints
    int*      boff = (int*)(ws + 35000320);      // SC_BLOCKS+1 ints
    uint_t*   Wg   = (uint_t*)(ws + 35000576);   // 4096 u32 packed bf16 W (16 KB)

    hipMemsetAsync(cnt, 0, 400000, stream);       // cnt + fil (contiguous)
    hipMemsetAsync(tm, 0, 6400000, stream);       // last_tm_signal = 0

    k_hist<<<(NE + 255) / 256, 256, 0, stream>>>(ei, cnt);
    k_scanA<<<SC_BLOCKS, 256, 0, stream>>>(cnt, bsum);
    k_scanB<<<1, 64, 0, stream>>>(bsum, boff);
    k_scanC<<<SC_BLOCKS, 256, 0, stream>>>(cnt, boff, rp);
    k_fill<<<(NE + 255) / 256, 256, 0, stream>>>(ei, rp, fil, col);
    k_prepW<<<16, 256, 0, stream>>>(W_tm, Wg);

    k_mlp<<<1563, 256, 0, stream>>>(x, W_in, b_in, g_in, be_in, h2A);

    k_flayer<<<NN / 4, 256, 0, stream>>>(h2A, h2B, rp, col, Wg, b_tm, tm_g, tm_b, tm, 0);
    k_flayer<<<NN / 4, 256, 0, stream>>>(h2B, h2A, rp, col, Wg, b_tm, tm_g, tm_b, tm, 1);
    k_flayer<<<NN / 4, 256, 0, stream>>>(h2A, h2B, rp, col, Wg, b_tm, tm_g, tm_b, tm, 2);

    k_pool<<<NG, 1024, 0, stream>>>(h2B, batch, out);
}

// Round 14
// 300.381 us; speedup vs baseline: 2.1137x; 1.0607x over previous
//
#include <hip/hip_runtime.h>

#define NN 50000      // nodes
#define NE 600000     // edges
#define HC 128        // hidden channels
#define CHN 32        // chunk size
#define NG 64         // graphs
#define LN_EPS 1e-5f

typedef unsigned short ushort_t;
typedef unsigned int uint_t;
typedef _Float16 half2_t __attribute__((ext_vector_type(2)));

__device__ __forceinline__ ushort_t f2h(float f) {    // f32 -> f16 (RNE)
    _Float16 h = (_Float16)f;
    return __builtin_bit_cast(ushort_t, h);
}
__device__ __forceinline__ float h2f(ushort_t s) {
    _Float16 h = __builtin_bit_cast(_Float16, s);
    return (float)h;
}
__device__ __forceinline__ uint_t pkh(float e, float o) {   // pack 2 f16
    return (uint_t)f2h(e) | ((uint_t)f2h(o) << 16);
}
// z += a . b for packed f16 pairs, f32 accumulate (v_dot2_f32_f16)
__device__ __forceinline__ float dot2h(uint_t a, uint_t b, float c) {
#if __has_builtin(__builtin_amdgcn_fdot2)
    return __builtin_amdgcn_fdot2(__builtin_bit_cast(half2_t, a),
                                  __builtin_bit_cast(half2_t, b), c, false);
#else
    half2_t ha = __builtin_bit_cast(half2_t, a);
    half2_t hb = __builtin_bit_cast(half2_t, b);
    c = fmaf((float)ha.x, (float)hb.x, c);
    c = fmaf((float)ha.y, (float)hb.y, c);
    return c;
#endif
}

// ---------------- CSR build ----------------

__global__ void __launch_bounds__(256) k_hist(const int* __restrict__ ei, int* __restrict__ cnt) {
    int e = blockIdx.x * 256 + threadIdx.x;
    if (e >= NE) return;
    int s = ei[e], d = ei[NE + e];
    if (s != d) atomicAdd(&cnt[d], 1);
}

#define SC_BLOCKS 49   // ceil(50000/1024)

__global__ void __launch_bounds__(256) k_scanA(const int* __restrict__ cnt, int* __restrict__ blocksum) {
    int b = blockIdx.x, t = threadIdx.x;
    int idx = b * 1024 + t * 4;
    int4 v = make_int4(0, 0, 0, 0);
    if (idx + 3 < NN) v = *(const int4*)&cnt[idx];
    else {
        if (idx + 0 < NN) v.x = cnt[idx + 0];
        if (idx + 1 < NN) v.y = cnt[idx + 1];
        if (idx + 2 < NN) v.z = cnt[idx + 2];
        if (idx + 3 < NN) v.w = cnt[idx + 3];
    }
    int s = v.x + v.y + v.z + v.w;
    for (int m = 1; m < 64; m <<= 1) s += __shfl_xor(s, m, 64);
    __shared__ int ws[4];
    if ((t & 63) == 0) ws[t >> 6] = s;
    __syncthreads();
    if (t == 0) blocksum[b] = ws[0] + ws[1] + ws[2] + ws[3];
}

__global__ void __launch_bounds__(64) k_scanB(const int* __restrict__ blocksum, int* __restrict__ blockoff) {
    int t = threadIdx.x;
    int v = (t < SC_BLOCKS) ? blocksum[t] : 0;
    int inc = v;
    for (int d = 1; d < 64; d <<= 1) { int u = __shfl_up(inc, d, 64); if (t >= d) inc += u; }
    if (t < SC_BLOCKS) blockoff[t + 1] = inc;
    if (t == 0) blockoff[0] = 0;
}

__global__ void __launch_bounds__(256) k_scanC(const int* __restrict__ cnt, const int* __restrict__ blockoff,
                                               int* __restrict__ row_ptr) {
    int b = blockIdx.x, t = threadIdx.x;
    int idx = b * 1024 + t * 4;
    int4 v = make_int4(0, 0, 0, 0);
    if (idx + 3 < NN) v = *(const int4*)&cnt[idx];
    else {
        if (idx + 0 < NN) v.x = cnt[idx + 0];
        if (idx + 1 < NN) v.y = cnt[idx + 1];
        if (idx + 2 < NN) v.z = cnt[idx + 2];
        if (idx + 3 < NN) v.w = cnt[idx + 3];
    }
    int s = v.x + v.y + v.z + v.w;
    int lane = t & 63, w = t >> 6;
    int inc = s;
    for (int d = 1; d < 64; d <<= 1) { int u = __shfl_up(inc, d, 64); if (lane >= d) inc += u; }
    __shared__ int wsum[4];
    if (lane == 63) wsum[w] = inc;
    __syncthreads();
    int off = blockoff[b];
    for (int i = 0; i < w; ++i) off += wsum[i];
    int excl = off + inc - s;
    if (idx + 0 < NN) row_ptr[idx + 0] = excl;
    if (idx + 1 < NN) row_ptr[idx + 1] = excl + v.x;
    if (idx + 2 < NN) row_ptr[idx + 2] = excl + v.x + v.y;
    if (idx + 3 < NN) row_ptr[idx + 3] = excl + v.x + v.y + v.z;
    if (b == 0 && t == 0) row_ptr[NN] = blockoff[SC_BLOCKS];
}

__global__ void __launch_bounds__(256) k_fill(const int* __restrict__ ei, const int* __restrict__ row_ptr,
                                              int* __restrict__ fill, int* __restrict__ col) {
    int e = blockIdx.x * 256 + threadIdx.x;
    if (e >= NE) return;
    int s = ei[e], d = ei[NE + e];
    if (s != d) {
        int pos = atomicAdd(&fill[d], 1);
        col[row_ptr[d] + pos] = s;
    }
}

// ---------------- pack W_tm once: Wg[cp*32+k] = f16pair(W[2cp][k], W[2cp+1][k]) ----------------

__global__ void __launch_bounds__(256) k_prepW(const float* __restrict__ Wtm, uint_t* __restrict__ Wg) {
    int i = blockIdx.x * 256 + threadIdx.x;
    if (i >= (HC / 2) * 2 * CHN) return;          // 128*32 = 4096 entries
    int cp = i >> 5, kk = i & 31;
    Wg[i] = pkh(Wtm[(2 * cp) * CHN + kk], Wtm[(2 * cp + 1) * CHN + kk]);
}

// ---------------- input MLP: h2 = f16(LN(relu(x @ W_in + b_in))) ----------------

#define MLP_NB 8
#define MLP_GROUPS (NN / MLP_NB)   // 6250, exact

__global__ void __launch_bounds__(256) k_mlp(const float* __restrict__ x, const float* __restrict__ W,
                                             const float* __restrict__ b, const float* __restrict__ g,
                                             const float* __restrict__ be, ushort_t* __restrict__ h2) {
    __shared__ float xs[4][MLP_NB][HC];     // 16 KB
    int tid = threadIdx.x;
    int wave = tid >> 6, lane = tid & 63;
    float bx = b[2 * lane],  by = b[2 * lane + 1];
    float gx = g[2 * lane],  gy = g[2 * lane + 1];
    float bex = be[2 * lane], bey = be[2 * lane + 1];
    for (int grp = blockIdx.x * 4 + wave; grp < MLP_GROUPS; grp += gridDim.x * 4) {
        int base = grp * MLP_NB;
        #pragma unroll
        for (int nb = 0; nb < MLP_NB; ++nb) {
            float2 xv = *(const float2*)&x[(size_t)(base + nb) * HC + 2 * lane];
            *(float2*)&xs[wave][nb][2 * lane] = xv;
        }
        float ax[MLP_NB], ay[MLP_NB];
        #pragma unroll
        for (int nb = 0; nb < MLP_NB; ++nb) { ax[nb] = bx; ay[nb] = by; }
        // wave-local LDS: compiler inserts lgkmcnt waits; no block barrier needed
        for (int c = 0; c < HC; c += 4) {
            float2 wv0 = *(const float2*)&W[(c + 0) * HC + 2 * lane];
            float2 wv1 = *(const float2*)&W[(c + 1) * HC + 2 * lane];
            float2 wv2 = *(const float2*)&W[(c + 2) * HC + 2 * lane];
            float2 wv3 = *(const float2*)&W[(c + 3) * HC + 2 * lane];
            #pragma unroll
            for (int nb = 0; nb < MLP_NB; ++nb) {
                float4 xv = *(const float4*)&xs[wave][nb][c];
                ax[nb] = fmaf(xv.x, wv0.x, ax[nb]); ay[nb] = fmaf(xv.x, wv0.y, ay[nb]);
                ax[nb] = fmaf(xv.y, wv1.x, ax[nb]); ay[nb] = fmaf(xv.y, wv1.y, ay[nb]);
                ax[nb] = fmaf(xv.z, wv2.x, ax[nb]); ay[nb] = fmaf(xv.z, wv2.y, ay[nb]);
                ax[nb] = fmaf(xv.w, wv3.x, ax[nb]); ay[nb] = fmaf(xv.w, wv3.y, ay[nb]);
            }
        }
        #pragma unroll
        for (int nb = 0; nb < MLP_NB; ++nb) {
            float a0 = fmaxf(ax[nb], 0.f), a1 = fmaxf(ay[nb], 0.f);
            float sm = a0 + a1;
            for (int m = 1; m < 64; m <<= 1) sm += __shfl_xor(sm, m, 64);
            float mu = sm * (1.f / 128.f);
            float d0 = a0 - mu, d1 = a1 - mu;
            float vv = d0 * d0 + d1 * d1;
            for (int m = 1; m < 64; m <<= 1) vv += __shfl_xor(vv, m, 64);
            float inv = rsqrtf(vv * (1.f / 128.f) + LN_EPS);
            float ox = d0 * inv * gx + bex;
            float oy = d1 * inv * gy + bey;
            *(uint_t*)&h2[(size_t)(base + nb) * HC + 2 * lane] = pkh(ox, oy);
        }
    }
}

// ---------------- fused layer: gather + mean + gating + mix + LN (f16 state) ----------------
// R13's occupancy-first shape (1 node/wave, 12500 blocks, LDS 2 KB, VGPR 32,
// 70% occ) with VALU-count cuts (R13 was 95% VALUBusy):
//  (a) gather accumulates packed f16 (v_pk_add_f16): 1 VALU/edge, was 4.
//  (b) z-loop uses v_dot2_f32_f16 (f32 accum): 64 VALU, was 256.
//  (c) self-row stages to LDS as the raw loaded u32 (no repack); __expf.
// f16 has more mantissa than bf16 at |h|<=~11, so precision is not degraded.

__global__ void __launch_bounds__(256) k_flayer(
        const ushort_t* __restrict__ h2in, ushort_t* __restrict__ h2out,
        const int* __restrict__ row_ptr, const int* __restrict__ col,
        const uint_t* __restrict__ Wg, const float* __restrict__ btm,
        const float* __restrict__ gall, const float* __restrict__ ball,
        float* __restrict__ tm, int layer) {
    __shared__ uint_t hm_pk[4][2][64];   // 2 KB: [wave][h|m][pair]
    int tid = threadIdx.x;
    int wave = tid >> 6, lane = tid & 63;
    int k = lane & 31, half = lane >> 5;
    int node = blockIdx.x * 4 + wave;
    int r0 = row_ptr[node], r1 = row_ptr[node + 1];
    int deg = r1 - r0;
    float tmo = tm[(size_t)node * CHN + k];   // prefetch, hides under gather
    float bk  = btm[k];
    float gx  = gall[layer * HC + 2 * lane], gy  = gall[layer * HC + 2 * lane + 1];
    float bex = ball[layer * HC + 2 * lane], bey = ball[layer * HC + 2 * lane + 1];
    // ---- gather-sum over in-neighbors: packed-f16 accumulate (1 pk_add/edge) ----
    half2_t acc = (half2_t)(_Float16)0;
    for (int base = 0; base < deg; base += 64) {
        int nIdx = min(64, deg - base);
        int myc = (base + lane < deg) ? col[r0 + base + lane] : 0;
        int j = 0;
        for (; j + 4 <= nIdx; j += 4) {
            int s0 = __shfl(myc, j,     64);
            int s1 = __shfl(myc, j + 1, 64);
            int s2 = __shfl(myc, j + 2, 64);
            int s3 = __shfl(myc, j + 3, 64);
            uint_t v0 = *(const uint_t*)&h2in[(size_t)s0 * HC + 2 * lane];
            uint_t v1 = *(const uint_t*)&h2in[(size_t)s1 * HC + 2 * lane];
            uint_t v2 = *(const uint_t*)&h2in[(size_t)s2 * HC + 2 * lane];
            uint_t v3 = *(const uint_t*)&h2in[(size_t)s3 * HC + 2 * lane];
            acc += __builtin_bit_cast(half2_t, v0);
            acc += __builtin_bit_cast(half2_t, v1);
            acc += __builtin_bit_cast(half2_t, v2);
            acc += __builtin_bit_cast(half2_t, v3);
        }
        for (; j < nIdx; ++j) {
            int s = __shfl(myc, j, 64);
            uint_t v = *(const uint_t*)&h2in[(size_t)s * HC + 2 * lane];
            acc += __builtin_bit_cast(half2_t, v);
        }
    }
    float ax = (float)acc.x, ay = (float)acc.y;
    // ---- self row, mean ----
    uint_t hvp = *(const uint_t*)&h2in[(size_t)node * HC + 2 * lane];
    float h0 = h2f((ushort_t)(hvp & 0xFFFFu)), h1 = h2f((ushort_t)(hvp >> 16));
    float invdeg = 1.f / (float)(deg + 1);
    float m0 = (ax + h0) * invdeg, m1 = (ay + h1) * invdeg;
    hm_pk[wave][0][lane] = hvp;              // raw self row, no repack
    hm_pk[wave][1][lane] = pkh(m0, m1);
    // wave-local LDS: compiler inserts the lgkmcnt wait; no block barrier needed
    // ---- z_k: half 0 = h . W[0:128,k], half 1 = m . W[128:256,k] (v_dot2) ----
    const uint_t* sp = &hm_pk[wave][half][0];
    const uint_t* wp = Wg + (size_t)(half * 64) * CHN + k;
    float z = 0.f;
    #pragma unroll
    for (int i = 0; i < 16; ++i) {
        uint4 s4 = *(const uint4*)&sp[4 * i];       // LDS broadcast
        uint_t w0 = wp[(4 * i + 0) * CHN];
        uint_t w1 = wp[(4 * i + 1) * CHN];
        uint_t w2 = wp[(4 * i + 2) * CHN];
        uint_t w3 = wp[(4 * i + 3) * CHN];
        z = dot2h(s4.x, w0, z);
        z = dot2h(s4.y, w1, z);
        z = dot2h(s4.z, w2, z);
        z = dot2h(s4.w, w3, z);
    }
    z += __shfl_xor(z, 32, 64);      // combine halves -> full z_k on all lanes
    z += bk;
    // ---- softmax over 32 gates (width-32: halves identical) ----
    float mx = z;
    for (int m = 1; m < 32; m <<= 1) mx = fmaxf(mx, __shfl_xor(mx, m, 32));
    float e = __expf(z - mx);
    float se = e;
    for (int m = 1; m < 32; m <<= 1) se += __shfl_xor(se, m, 32);
    float p = e / se;
    // inclusive cumsum over gate index
    float cum = p;
    for (int d = 1; d < 32; d <<= 1) {
        float t2 = __shfl_up(cum, d, 32);
        if (k >= d) cum += t2;
    }
    float raw = tmo + (1.f - tmo) * cum;
    if (half == 0) tm[(size_t)node * CHN + k] = raw;
    // sig for channels (2*lane, 2*lane+1): gate = lane>>1
    float sig = __shfl(raw, lane >> 1, 64);
    float v0 = h0 * sig + m0 * (1.f - sig);
    float v1 = h1 * sig + m1 * (1.f - sig);
    // ---- LN over 128 ch (width-64 reduce, 2 ch/lane) ----
    float sm = v0 + v1;
    for (int m = 1; m < 64; m <<= 1) sm += __shfl_xor(sm, m, 64);
    float mu = sm * (1.f / 128.f);
    float d0 = v0 - mu, d1 = v1 - mu;
    float vv = d0 * d0 + d1 * d1;
    for (int m = 1; m < 64; m <<= 1) vv += __shfl_xor(vv, m, 64);
    float inv = rsqrtf(vv * (1.f / 128.f) + LN_EPS);
    *(uint_t*)&h2out[(size_t)node * HC + 2 * lane] = pkh(d0 * inv * gx + bex,
                                                         d1 * inv * gy + bey);
}

// ---------------- global mean pool (batch is sorted), f16 input ----------------

__global__ void __launch_bounds__(1024) k_pool(const ushort_t* __restrict__ h2, const int* __restrict__ batch,
                                               float* __restrict__ out) {
    __shared__ float red[8][HC];
    int g = blockIdx.x;
    int tid = threadIdx.x;
    int c = tid & (HC - 1);
    int w = tid >> 7;          // 0..7 node-slice
    int a = 0, bnd = NN;
    while (a < bnd) { int mid = (a + bnd) >> 1; if (batch[mid] < g) a = mid + 1; else bnd = mid; }
    int start = a;
    bnd = NN;
    while (a < bnd) { int mid = (a + bnd) >> 1; if (batch[mid] <= g) a = mid + 1; else bnd = mid; }
    int end = a;
    float acc = 0.f;
    for (int n = start + w; n < end; n += 8) acc += h2f(h2[(size_t)n * HC + c]);
    red[w][c] = acc;
    __syncthreads();
    if (w == 0) {
        float s = red[0][c] + red[1][c] + red[2][c] + red[3][c]
                + red[4][c] + red[5][c] + red[6][c] + red[7][c];
        int count = end - start;
        out[g * HC + c] = s / (float)max(count, 1);
    }
}

// ---------------- launch ----------------

extern "C" void kernel_launch(void* const* d_in, const int* in_sizes, int n_in,
                              void* d_out, int out_size, void* d_ws, size_t ws_size,
                              hipStream_t stream) {
    const float* x     = (const float*)d_in[0];
    const int*   ei    = (const int*)d_in[1];
    const int*   batch = (const int*)d_in[2];
    const float* W_in  = (const float*)d_in[3];
    const float* b_in  = (const float*)d_in[4];
    const float* g_in  = (const float*)d_in[5];
    const float* be_in = (const float*)d_in[6];
    const float* W_tm  = (const float*)d_in[7];
    const float* b_tm  = (const float*)d_in[8];
    const float* tm_g  = (const float*)d_in[9];
    const float* tm_b  = (const float*)d_in[10];
    float* out = (float*)d_out;

    char* ws = (char*)d_ws;
    int*      cnt = (int*)(ws + 0);              // NN ints
    int*      fil = (int*)(ws + 200000);         // NN ints
    int*      rp  = (int*)(ws + 400000);         // NN+1 ints
    int*      col = (int*)(ws + 600004);         // NE ints   (ends at 3,000,004)
    ushort_t* h2A = (ushort_t*)(ws + 3000064);   // NN*HC f16 (12.8 MB)
    ushort_t* h2B = (ushort_t*)(ws + 15800064);  // NN*HC f16 (12.8 MB)
    float*    tm  = (float*)(ws + 28600064);     // NN*CHN fp32 (6.4 MB) -> 35,000,064
    int*      bsum = (int*)(ws + 35000064);      // SC_BLOCKS ints
    int*      boff = (int*)(ws + 35000320);      // SC_BLOCKS+1 ints
    uint_t*   Wg   = (uint_t*)(ws + 35000576);   // 4096 u32 packed f16 W (16 KB)

    hipMemsetAsync(cnt, 0, 400000, stream);       // cnt + fil (contiguous)
    hipMemsetAsync(tm, 0, 6400000, stream);       // last_tm_signal = 0

    k_hist<<<(NE + 255) / 256, 256, 0, stream>>>(ei, cnt);
    k_scanA<<<SC_BLOCKS, 256, 0, stream>>>(cnt, bsum);
    k_scanB<<<1, 64, 0, stream>>>(bsum, boff);
    k_scanC<<<SC_BLOCKS, 256, 0, stream>>>(cnt, boff, rp);
    k_fill<<<(NE + 255) / 256, 256, 0, stream>>>(ei, rp, fil, col);
    k_prepW<<<16, 256, 0, stream>>>(W_tm, Wg);

    k_mlp<<<1563, 256, 0, stream>>>(x, W_in, b_in, g_in, be_in, h2A);

    k_flayer<<<NN / 4, 256, 0, stream>>>(h2A, h2B, rp, col, Wg, b_tm, tm_g, tm_b, tm, 0);
    k_flayer<<<NN / 4, 256, 0, stream>>>(h2B, h2A, rp, col, Wg, b_tm, tm_g, tm_b, tm, 1);
    k_flayer<<<NN / 4, 256, 0, stream>>>(h2A, h2B, rp, col, Wg, b_tm, tm_g, tm_b, tm, 2);

    k_pool<<<NG, 1024, 0, stream>>>(h2B, batch, out);
}

// Round 15
// 288.423 us; speedup vs baseline: 2.2014x; 1.0415x over previous
//
#include <hip/hip_runtime.h>

#define NN 50000      // nodes
#define NE 600000     // edges
#define HC 128        // hidden channels
#define CHN 32        // chunk size
#define NG 64         // graphs
#define LN_EPS 1e-5f

typedef unsigned short ushort_t;
typedef unsigned int uint_t;
typedef _Float16 half2_t __attribute__((ext_vector_type(2)));

__device__ __forceinline__ ushort_t f2h(float f) {    // f32 -> f16 (RNE)
    _Float16 h = (_Float16)f;
    return __builtin_bit_cast(ushort_t, h);
}
__device__ __forceinline__ float h2f(ushort_t s) {
    _Float16 h = __builtin_bit_cast(_Float16, s);
    return (float)h;
}
__device__ __forceinline__ uint_t pkh(float e, float o) {   // pack 2 f16
    return (uint_t)f2h(e) | ((uint_t)f2h(o) << 16);
}
// z += a . b for packed f16 pairs, f32 accumulate (v_dot2_f32_f16)
__device__ __forceinline__ float dot2h(uint_t a, uint_t b, float c) {
#if __has_builtin(__builtin_amdgcn_fdot2)
    return __builtin_amdgcn_fdot2(__builtin_bit_cast(half2_t, a),
                                  __builtin_bit_cast(half2_t, b), c, false);
#else
    half2_t ha = __builtin_bit_cast(half2_t, a);
    half2_t hb = __builtin_bit_cast(half2_t, b);
    c = fmaf((float)ha.x, (float)hb.x, c);
    c = fmaf((float)ha.y, (float)hb.y, c);
    return c;
#endif
}

// ---------------- CSR build ----------------

__global__ void __launch_bounds__(256) k_hist(const int* __restrict__ ei, int* __restrict__ cnt) {
    int e = blockIdx.x * 256 + threadIdx.x;
    if (e >= NE) return;
    int s = ei[e], d = ei[NE + e];
    if (s != d) atomicAdd(&cnt[d], 1);
}

#define SC_BLOCKS 49   // ceil(50000/1024)

__global__ void __launch_bounds__(256) k_scanA(const int* __restrict__ cnt, int* __restrict__ blocksum) {
    int b = blockIdx.x, t = threadIdx.x;
    int idx = b * 1024 + t * 4;
    int4 v = make_int4(0, 0, 0, 0);
    if (idx + 3 < NN) v = *(const int4*)&cnt[idx];
    else {
        if (idx + 0 < NN) v.x = cnt[idx + 0];
        if (idx + 1 < NN) v.y = cnt[idx + 1];
        if (idx + 2 < NN) v.z = cnt[idx + 2];
        if (idx + 3 < NN) v.w = cnt[idx + 3];
    }
    int s = v.x + v.y + v.z + v.w;
    for (int m = 1; m < 64; m <<= 1) s += __shfl_xor(s, m, 64);
    __shared__ int ws[4];
    if ((t & 63) == 0) ws[t >> 6] = s;
    __syncthreads();
    if (t == 0) blocksum[b] = ws[0] + ws[1] + ws[2] + ws[3];
}

__global__ void __launch_bounds__(64) k_scanB(const int* __restrict__ blocksum, int* __restrict__ blockoff) {
    int t = threadIdx.x;
    int v = (t < SC_BLOCKS) ? blocksum[t] : 0;
    int inc = v;
    for (int d = 1; d < 64; d <<= 1) { int u = __shfl_up(inc, d, 64); if (t >= d) inc += u; }
    if (t < SC_BLOCKS) blockoff[t + 1] = inc;
    if (t == 0) blockoff[0] = 0;
}

__global__ void __launch_bounds__(256) k_scanC(const int* __restrict__ cnt, const int* __restrict__ blockoff,
                                               int* __restrict__ row_ptr) {
    int b = blockIdx.x, t = threadIdx.x;
    int idx = b * 1024 + t * 4;
    int4 v = make_int4(0, 0, 0, 0);
    if (idx + 3 < NN) v = *(const int4*)&cnt[idx];
    else {
        if (idx + 0 < NN) v.x = cnt[idx + 0];
        if (idx + 1 < NN) v.y = cnt[idx + 1];
        if (idx + 2 < NN) v.z = cnt[idx + 2];
        if (idx + 3 < NN) v.w = cnt[idx + 3];
    }
    int s = v.x + v.y + v.z + v.w;
    int lane = t & 63, w = t >> 6;
    int inc = s;
    for (int d = 1; d < 64; d <<= 1) { int u = __shfl_up(inc, d, 64); if (lane >= d) inc += u; }
    __shared__ int wsum[4];
    if (lane == 63) wsum[w] = inc;
    __syncthreads();
    int off = blockoff[b];
    for (int i = 0; i < w; ++i) off += wsum[i];
    int excl = off + inc - s;
    if (idx + 0 < NN) row_ptr[idx + 0] = excl;
    if (idx + 1 < NN) row_ptr[idx + 1] = excl + v.x;
    if (idx + 2 < NN) row_ptr[idx + 2] = excl + v.x + v.y;
    if (idx + 3 < NN) row_ptr[idx + 3] = excl + v.x + v.y + v.z;
    if (b == 0 && t == 0) row_ptr[NN] = blockoff[SC_BLOCKS];
}

__global__ void __launch_bounds__(256) k_fill(const int* __restrict__ ei, const int* __restrict__ row_ptr,
                                              int* __restrict__ fill, int* __restrict__ col) {
    int e = blockIdx.x * 256 + threadIdx.x;
    if (e >= NE) return;
    int s = ei[e], d = ei[NE + e];
    if (s != d) {
        int pos = atomicAdd(&fill[d], 1);
        col[row_ptr[d] + pos] = s;
    }
}

// ---------------- prep: pack W_tm to f16 pairs + zero cnt/fil (replaces memset) ----------------
// Wg[cp*32+k] = f16pair(W[2cp][k], W[2cp+1][k]); cnt and fil are contiguous (100000 ints).

__global__ void __launch_bounds__(256) k_prep(const float* __restrict__ Wtm, uint_t* __restrict__ Wg,
                                              int* __restrict__ cnt) {
    int i = blockIdx.x * 256 + threadIdx.x;
    if (i < (HC / 2) * 2 * CHN) {                 // 4096 entries
        int cp = i >> 5, kk = i & 31;
        Wg[i] = pkh(Wtm[(2 * cp) * CHN + kk], Wtm[(2 * cp + 1) * CHN + kk]);
    }
    for (int z = i; z < 2 * NN; z += gridDim.x * 256) cnt[z] = 0;   // cnt + fil
}

// ---------------- input MLP: h2 = f16(LN(relu(x @ W_in + b_in))); also zeros tm ----------------

#define MLP_NB 8
#define MLP_GROUPS (NN / MLP_NB)   // 6250, exact

__global__ void __launch_bounds__(256) k_mlp(const float* __restrict__ x, const float* __restrict__ W,
                                             const float* __restrict__ b, const float* __restrict__ g,
                                             const float* __restrict__ be, ushort_t* __restrict__ h2,
                                             float* __restrict__ tm) {
    // zero last_tm_signal (runs long before any flayer reads it)
    for (int z = blockIdx.x * 256 + threadIdx.x; z < NN * CHN; z += gridDim.x * 256) tm[z] = 0.f;
    __shared__ float xs[4][MLP_NB][HC];     // 16 KB
    int tid = threadIdx.x;
    int wave = tid >> 6, lane = tid & 63;
    float bx = b[2 * lane],  by = b[2 * lane + 1];
    float gx = g[2 * lane],  gy = g[2 * lane + 1];
    float bex = be[2 * lane], bey = be[2 * lane + 1];
    for (int grp = blockIdx.x * 4 + wave; grp < MLP_GROUPS; grp += gridDim.x * 4) {
        int base = grp * MLP_NB;
        #pragma unroll
        for (int nb = 0; nb < MLP_NB; ++nb) {
            float2 xv = *(const float2*)&x[(size_t)(base + nb) * HC + 2 * lane];
            *(float2*)&xs[wave][nb][2 * lane] = xv;
        }
        float ax[MLP_NB], ay[MLP_NB];
        #pragma unroll
        for (int nb = 0; nb < MLP_NB; ++nb) { ax[nb] = bx; ay[nb] = by; }
        // wave-local LDS: compiler inserts lgkmcnt waits; no block barrier needed
        for (int c = 0; c < HC; c += 4) {
            float2 wv0 = *(const float2*)&W[(c + 0) * HC + 2 * lane];
            float2 wv1 = *(const float2*)&W[(c + 1) * HC + 2 * lane];
            float2 wv2 = *(const float2*)&W[(c + 2) * HC + 2 * lane];
            float2 wv3 = *(const float2*)&W[(c + 3) * HC + 2 * lane];
            #pragma unroll
            for (int nb = 0; nb < MLP_NB; ++nb) {
                float4 xv = *(const float4*)&xs[wave][nb][c];
                ax[nb] = fmaf(xv.x, wv0.x, ax[nb]); ay[nb] = fmaf(xv.x, wv0.y, ay[nb]);
                ax[nb] = fmaf(xv.y, wv1.x, ax[nb]); ay[nb] = fmaf(xv.y, wv1.y, ay[nb]);
                ax[nb] = fmaf(xv.z, wv2.x, ax[nb]); ay[nb] = fmaf(xv.z, wv2.y, ay[nb]);
                ax[nb] = fmaf(xv.w, wv3.x, ax[nb]); ay[nb] = fmaf(xv.w, wv3.y, ay[nb]);
            }
        }
        #pragma unroll
        for (int nb = 0; nb < MLP_NB; ++nb) {
            float a0 = fmaxf(ax[nb], 0.f), a1 = fmaxf(ay[nb], 0.f);
            float sm = a0 + a1;
            for (int m = 1; m < 64; m <<= 1) sm += __shfl_xor(sm, m, 64);
            float mu = sm * (1.f / 128.f);
            float d0 = a0 - mu, d1 = a1 - mu;
            float vv = d0 * d0 + d1 * d1;
            for (int m = 1; m < 64; m <<= 1) vv += __shfl_xor(vv, m, 64);
            float inv = rsqrtf(vv * (1.f / 128.f) + LN_EPS);
            float ox = d0 * inv * gx + bex;
            float oy = d1 * inv * gy + bey;
            *(uint_t*)&h2[(size_t)(base + nb) * HC + 2 * lane] = pkh(ox, oy);
        }
    }
}

// ---------------- fused layer: gather + mean + gating + mix + LN (f16 state) ----------------
// R13/R14 occupancy-first shape (1 node/wave, 12500 blocks, LDS 2 KB) with the
// gather MLP deepened: 8 loads in flight per round (was 4) -> dependent rounds
// per node drop 3 -> 2 at avg deg 12. VGPR stays under the 64 cliff.

__global__ void __launch_bounds__(256) k_flayer(
        const ushort_t* __restrict__ h2in, ushort_t* __restrict__ h2out,
        const int* __restrict__ row_ptr, const int* __restrict__ col,
        const uint_t* __restrict__ Wg, const float* __restrict__ btm,
        const float* __restrict__ gall, const float* __restrict__ ball,
        float* __restrict__ tm, int layer) {
    __shared__ uint_t hm_pk[4][2][64];   // 2 KB: [wave][h|m][pair]
    int tid = threadIdx.x;
    int wave = tid >> 6, lane = tid & 63;
    int k = lane & 31, half = lane >> 5;
    int node = blockIdx.x * 4 + wave;
    int r0 = row_ptr[node], r1 = row_ptr[node + 1];
    int deg = r1 - r0;
    float tmo = tm[(size_t)node * CHN + k];   // prefetch, hides under gather
    float bk  = btm[k];
    float gx  = gall[layer * HC + 2 * lane], gy  = gall[layer * HC + 2 * lane + 1];
    float bex = ball[layer * HC + 2 * lane], bey = ball[layer * HC + 2 * lane + 1];
    // ---- gather-sum over in-neighbors: packed-f16 accumulate, 8 loads in flight ----
    half2_t acc = (half2_t)(_Float16)0;
    for (int base = 0; base < deg; base += 64) {
        int nIdx = min(64, deg - base);
        int myc = (base + lane < deg) ? col[r0 + base + lane] : 0;
        int j = 0;
        for (; j + 8 <= nIdx; j += 8) {
            int s0 = __shfl(myc, j,     64);
            int s1 = __shfl(myc, j + 1, 64);
            int s2 = __shfl(myc, j + 2, 64);
            int s3 = __shfl(myc, j + 3, 64);
            int s4 = __shfl(myc, j + 4, 64);
            int s5 = __shfl(myc, j + 5, 64);
            int s6 = __shfl(myc, j + 6, 64);
            int s7 = __shfl(myc, j + 7, 64);
            uint_t v0 = *(const uint_t*)&h2in[(size_t)s0 * HC + 2 * lane];
            uint_t v1 = *(const uint_t*)&h2in[(size_t)s1 * HC + 2 * lane];
            uint_t v2 = *(const uint_t*)&h2in[(size_t)s2 * HC + 2 * lane];
            uint_t v3 = *(const uint_t*)&h2in[(size_t)s3 * HC + 2 * lane];
            uint_t v4 = *(const uint_t*)&h2in[(size_t)s4 * HC + 2 * lane];
            uint_t v5 = *(const uint_t*)&h2in[(size_t)s5 * HC + 2 * lane];
            uint_t v6 = *(const uint_t*)&h2in[(size_t)s6 * HC + 2 * lane];
            uint_t v7 = *(const uint_t*)&h2in[(size_t)s7 * HC + 2 * lane];
            acc += __builtin_bit_cast(half2_t, v0);
            acc += __builtin_bit_cast(half2_t, v1);
            acc += __builtin_bit_cast(half2_t, v2);
            acc += __builtin_bit_cast(half2_t, v3);
            acc += __builtin_bit_cast(half2_t, v4);
            acc += __builtin_bit_cast(half2_t, v5);
            acc += __builtin_bit_cast(half2_t, v6);
            acc += __builtin_bit_cast(half2_t, v7);
        }
        for (; j + 4 <= nIdx; j += 4) {
            int s0 = __shfl(myc, j,     64);
            int s1 = __shfl(myc, j + 1, 64);
            int s2 = __shfl(myc, j + 2, 64);
            int s3 = __shfl(myc, j + 3, 64);
            uint_t v0 = *(const uint_t*)&h2in[(size_t)s0 * HC + 2 * lane];
            uint_t v1 = *(const uint_t*)&h2in[(size_t)s1 * HC + 2 * lane];
            uint_t v2 = *(const uint_t*)&h2in[(size_t)s2 * HC + 2 * lane];
            uint_t v3 = *(const uint_t*)&h2in[(size_t)s3 * HC + 2 * lane];
            acc += __builtin_bit_cast(half2_t, v0);
            acc += __builtin_bit_cast(half2_t, v1);
            acc += __builtin_bit_cast(half2_t, v2);
            acc += __builtin_bit_cast(half2_t, v3);
        }
        for (; j < nIdx; ++j) {
            int s = __shfl(myc, j, 64);
            uint_t v = *(const uint_t*)&h2in[(size_t)s * HC + 2 * lane];
            acc += __builtin_bit_cast(half2_t, v);
        }
    }
    float ax = (float)acc.x, ay = (float)acc.y;
    // ---- self row, mean ----
    uint_t hvp = *(const uint_t*)&h2in[(size_t)node * HC + 2 * lane];
    float h0 = h2f((ushort_t)(hvp & 0xFFFFu)), h1 = h2f((ushort_t)(hvp >> 16));
    float invdeg = 1.f / (float)(deg + 1);
    float m0 = (ax + h0) * invdeg, m1 = (ay + h1) * invdeg;
    hm_pk[wave][0][lane] = hvp;              // raw self row, no repack
    hm_pk[wave][1][lane] = pkh(m0, m1);
    // wave-local LDS: compiler inserts the lgkmcnt wait; no block barrier needed
    // ---- z_k: half 0 = h . W[0:128,k], half 1 = m . W[128:256,k] (v_dot2) ----
    const uint_t* sp = &hm_pk[wave][half][0];
    const uint_t* wp = Wg + (size_t)(half * 64) * CHN + k;
    float z = 0.f;
    #pragma unroll
    for (int i = 0; i < 16; ++i) {
        uint4 s4 = *(const uint4*)&sp[4 * i];       // LDS broadcast
        uint_t w0 = wp[(4 * i + 0) * CHN];
        uint_t w1 = wp[(4 * i + 1) * CHN];
        uint_t w2 = wp[(4 * i + 2) * CHN];
        uint_t w3 = wp[(4 * i + 3) * CHN];
        z = dot2h(s4.x, w0, z);
        z = dot2h(s4.y, w1, z);
        z = dot2h(s4.z, w2, z);
        z = dot2h(s4.w, w3, z);
    }
    z += __shfl_xor(z, 32, 64);      // combine halves -> full z_k on all lanes
    z += bk;
    // ---- softmax over 32 gates (width-32: halves identical) ----
    float mx = z;
    for (int m = 1; m < 32; m <<= 1) mx = fmaxf(mx, __shfl_xor(mx, m, 32));
    float e = __expf(z - mx);
    float se = e;
    for (int m = 1; m < 32; m <<= 1) se += __shfl_xor(se, m, 32);
    float p = e / se;
    // inclusive cumsum over gate index
    float cum = p;
    for (int d = 1; d < 32; d <<= 1) {
        float t2 = __shfl_up(cum, d, 32);
        if (k >= d) cum += t2;
    }
    float raw = tmo + (1.f - tmo) * cum;
    if (half == 0) tm[(size_t)node * CHN + k] = raw;
    // sig for channels (2*lane, 2*lane+1): gate = lane>>1
    float sig = __shfl(raw, lane >> 1, 64);
    float v0 = h0 * sig + m0 * (1.f - sig);
    float v1 = h1 * sig + m1 * (1.f - sig);
    // ---- LN over 128 ch (width-64 reduce, 2 ch/lane) ----
    float sm = v0 + v1;
    for (int m = 1; m < 64; m <<= 1) sm += __shfl_xor(sm, m, 64);
    float mu = sm * (1.f / 128.f);
    float d0 = v0 - mu, d1 = v1 - mu;
    float vv = d0 * d0 + d1 * d1;
    for (int m = 1; m < 64; m <<= 1) vv += __shfl_xor(vv, m, 64);
    float inv = rsqrtf(vv * (1.f / 128.f) + LN_EPS);
    *(uint_t*)&h2out[(size_t)node * HC + 2 * lane] = pkh(d0 * inv * gx + bex,
                                                         d1 * inv * gy + bey);
}

// ---------------- global mean pool (batch is sorted), f16 input ----------------

__global__ void __launch_bounds__(1024) k_pool(const ushort_t* __restrict__ h2, const int* __restrict__ batch,
                                               float* __restrict__ out) {
    __shared__ float red[8][HC];
    int g = blockIdx.x;
    int tid = threadIdx.x;
    int c = tid & (HC - 1);
    int w = tid >> 7;          // 0..7 node-slice
    int a = 0, bnd = NN;
    while (a < bnd) { int mid = (a + bnd) >> 1; if (batch[mid] < g) a = mid + 1; else bnd = mid; }
    int start = a;
    bnd = NN;
    while (a < bnd) { int mid = (a + bnd) >> 1; if (batch[mid] <= g) a = mid + 1; else bnd = mid; }
    int end = a;
    float acc = 0.f;
    for (int n = start + w; n < end; n += 8) acc += h2f(h2[(size_t)n * HC + c]);
    red[w][c] = acc;
    __syncthreads();
    if (w == 0) {
        float s = red[0][c] + red[1][c] + red[2][c] + red[3][c]
                + red[4][c] + red[5][c] + red[6][c] + red[7][c];
        int count = end - start;
        out[g * HC + c] = s / (float)max(count, 1);
    }
}

// ---------------- launch ----------------

extern "C" void kernel_launch(void* const* d_in, const int* in_sizes, int n_in,
                              void* d_out, int out_size, void* d_ws, size_t ws_size,
                              hipStream_t stream) {
    const float* x     = (const float*)d_in[0];
    const int*   ei    = (const int*)d_in[1];
    const int*   batch = (const int*)d_in[2];
    const float* W_in  = (const float*)d_in[3];
    const float* b_in  = (const float*)d_in[4];
    const float* g_in  = (const float*)d_in[5];
    const float* be_in = (const float*)d_in[6];
    const float* W_tm  = (const float*)d_in[7];
    const float* b_tm  = (const float*)d_in[8];
    const float* tm_g  = (const float*)d_in[9];
    const float* tm_b  = (const float*)d_in[10];
    float* out = (float*)d_out;

    char* ws = (char*)d_ws;
    int*      cnt = (int*)(ws + 0);              // NN ints
    int*      fil = (int*)(ws + 200000);         // NN ints (contiguous after cnt)
    int*      rp  = (int*)(ws + 400000);         // NN+1 ints
    int*      col = (int*)(ws + 600004);         // NE ints   (ends at 3,000,004)
    ushort_t* h2A = (ushort_t*)(ws + 3000064);   // NN*HC f16 (12.8 MB)
    ushort_t* h2B = (ushort_t*)(ws + 15800064);  // NN*HC f16 (12.8 MB)
    float*    tm  = (float*)(ws + 28600064);     // NN*CHN fp32 (6.4 MB) -> 35,000,064
    int*      bsum = (int*)(ws + 35000064);      // SC_BLOCKS ints
    int*      boff = (int*)(ws + 35000320);      // SC_BLOCKS+1 ints
    uint_t*   Wg   = (uint_t*)(ws + 35000576);   // 4096 u32 packed f16 W (16 KB)

    k_prep<<<64, 256, 0, stream>>>(W_tm, Wg, cnt);      // pack W + zero cnt/fil
    k_hist<<<(NE + 255) / 256, 256, 0, stream>>>(ei, cnt);
    k_scanA<<<SC_BLOCKS, 256, 0, stream>>>(cnt, bsum);
    k_scanB<<<1, 64, 0, stream>>>(bsum, boff);
    k_scanC<<<SC_BLOCKS, 256, 0, stream>>>(cnt, boff, rp);
    k_fill<<<(NE + 255) / 256, 256, 0, stream>>>(ei, rp, fil, col);

    k_mlp<<<1563, 256, 0, stream>>>(x, W_in, b_in, g_in, be_in, h2A, tm);  // also zeros tm

    k_flayer<<<NN / 4, 256, 0, stream>>>(h2A, h2B, rp, col, Wg, b_tm, tm_g, tm_b, tm, 0);
    k_flayer<<<NN / 4, 256, 0, stream>>>(h2B, h2A, rp, col, Wg, b_tm, tm_g, tm_b, tm, 1);
    k_flayer<<<NN / 4, 256, 0, stream>>>(h2A, h2B, rp, col, Wg, b_tm, tm_g, tm_b, tm, 2);

    k_pool<<<NG, 1024, 0, stream>>>(h2B, batch, out);
}